// Round 18
// baseline (164.623 us; speedup 1.0000x reference)
//
#include <hip/hip_runtime.h>
#include <cstdint>
#include <cstddef>

#define N_  32
#define C_  64
#define T_  256
#define V_  25
#define R_  8
#define O_  64
#define K_  5
#define NU_ 17
#define U_  25
#define CV  (C_ * V_)        // 1600
#define OG  2                // o's per block (tier-1 and tier-2 k_main)
#define NB  (OG * 32)        // 64 ncols (tier-2)

#define OUT_ELEMS ((size_t)N_ * O_ * T_ * V_)   // 13,107,200

typedef __attribute__((ext_vector_type(8))) short bf16x8;
typedef __attribute__((ext_vector_type(4))) float f32x4;

static __device__ __forceinline__ unsigned short f2bf(float f) {
    union { float f; unsigned u; } c; c.f = f;
    return (unsigned short)((c.u + 0x8000u) >> 16);
}
static __device__ __forceinline__ float bf2f(unsigned short h) {
    union { unsigned u; float f; } c; c.u = ((unsigned)h) << 16; return c.f;
}
static __device__ __forceinline__ float bf_lo(unsigned d) {
    union { unsigned u; float f; } c; c.u = d << 16; return c.f;
}
static __device__ __forceinline__ float bf_hi(unsigned d) {
    union { unsigned u; float f; } c; c.u = d & 0xFFFF0000u; return c.f;
}
static __device__ __forceinline__ unsigned pk2(float a, float b) {
    union { float f; unsigned u; } ca, cb; ca.f = a; cb.f = b;
    return ((ca.u + 0x8000u) >> 16) | ((cb.u + 0x8000u) & 0xFFFF0000u);
}
static __device__ __forceinline__ unsigned cvtpk(float a, float b) {
    unsigned r;
    asm("v_cvt_pk_bf16_f32 %0, %1, %2" : "=v"(r) : "v"(a), "v"(b));
    return r;
}
static __device__ __forceinline__ bf16x8 asbf(uint4 u) {
    union { uint4 u; bf16x8 h; } c; c.u = u; return c.h;
}
// LDS swizzle class for x2f: 8 classes, t and t+8 land in different classes.
static __device__ __forceinline__ int swzc(int t) {
    return ((t ^ (t >> 3)) & 7) << 2;
}

// ---------------------------------------------------------------------------
// k_xcast: fragment-native xT3 with cv' = v*64+c ordering:
//   xT3[n][tt(16)][s'(200)][tl(16)][ke(8)],  s' = v*8 + c/8, ke = c&7.
// ---------------------------------------------------------------------------
__global__ void k_xcast(const float* __restrict__ x, unsigned short* __restrict__ xT3,
                        float* __restrict__ pp) {
    __shared__ unsigned short tile[C_][408];   // [c][t*25+v], row 816 B
    int bid = blockIdx.x;
    int n = bid >> 4, tb = bid & 15;
    int tid = threadIdx.x;
    const float* xb = x + (size_t)n * C_ * T_ * V_ + tb * 400;
#pragma unroll
    for (int it = 0; it < 25; ++it) {
        int i = it * 256 + tid;          // < 6400
        int c = i / 100, q = i - c * 100;
        float4 v4 = *(const float4*)(xb + (size_t)c * (T_ * V_) + q * 4);
        uint2 w;
        w.x = pk2(v4.x, v4.y);
        w.y = pk2(v4.z, v4.w);
        *(uint2*)&tile[c][q * 4] = w;
    }
    __syncthreads();
    unsigned short* dstb = xT3 + ((size_t)(n * 16 + tb) * 200) * 128;
    for (int i = tid; i < 200 * 16; i += 256) {
        int sp = i >> 4, tl = i & 15;
        int v = sp >> 3, c0 = (sp & 7) * 8;
        unsigned short h[8];
#pragma unroll
        for (int j = 0; j < 8; ++j) h[j] = tile[c0 + j][tl * 25 + v];
        uint4 pk;
        pk.x = (unsigned)h[0] | ((unsigned)h[1] << 16);
        pk.y = (unsigned)h[2] | ((unsigned)h[3] << 16);
        pk.z = (unsigned)h[4] | ((unsigned)h[5] << 16);
        pk.w = (unsigned)h[6] | ((unsigned)h[7] << 16);
        *(uint4*)(dstb + (size_t)sp * 128 + tl * 8) = pk;
    }
    float* ppd = pp + ((size_t)n * 16 + tb) * CV;
    for (int e = tid; e < CV; e += 256) {
        int c = e / 25, v = e - c * 25;
        float s = 0.f;
#pragma unroll
        for (int t = 0; t < 16; ++t) s += bf2f(tile[c][t * 25 + v]);
        ppd[e] = s;
    }
}

// classic pool (slow tier)
__global__ void k_pool(const float* __restrict__ x, float* __restrict__ pool) {
    int nc = blockIdx.x;
    int t  = threadIdx.x;
    const float* px = x + ((size_t)nc * T_ + t) * V_;
    float acc[V_];
#pragma unroll
    for (int v = 0; v < V_; ++v) acc[v] = px[v];
#pragma unroll
    for (int off = 32; off > 0; off >>= 1) {
#pragma unroll
        for (int v = 0; v < V_; ++v) acc[v] += __shfl_down(acc[v], off, 64);
    }
    __shared__ float sm[4][V_];
    int wave = t >> 6, lane = t & 63;
    if (lane == 0) {
#pragma unroll
        for (int v = 0; v < V_; ++v) sm[wave][v] = acc[v];
    }
    __syncthreads();
    if (t < V_) {
        float s = sm[0][t] + sm[1][t] + sm[2][t] + sm[3][t];
        pool[(size_t)nc * V_ + t] = s * (1.0f / T_);
    }
}

// ---------------------------------------------------------------------------
// k_tvals (slow tier only)
// ---------------------------------------------------------------------------
__global__ void k_tvals(const float* __restrict__ pool,
                        const float* __restrict__ W11, const float* __restrict__ b11,
                        const float* __restrict__ W12, const float* __restrict__ b12,
                        const float* __restrict__ W2,  const float* __restrict__ b2,
                        float* __restrict__ t2o, float* __restrict__ tSo) {
    int kn = blockIdx.x;
    int k = kn / N_, n = kn % N_;
    int tid = threadIdx.x;
    int r = tid >> 5, v = tid & 31;
    if (v >= V_) return;
    const float* pp = pool + (size_t)n * C_ * V_ + v;
    const float* w2 = W2 + ((size_t)k * R_ + r) * C_;
    const float* w1 = ((v < NU_) ? W11 : W12) + ((size_t)k * R_ + r) * C_;
    float a2 = b2[k * R_ + r];
    float a1 = (v < NU_) ? b11[k * R_ + r] : b12[k * R_ + r];
    for (int c = 0; c < C_; ++c) {
        float p = pp[(size_t)c * V_];
        a2 += w2[c] * p;
        a1 += w1[c] * p;
    }
    size_t idx = (((size_t)k * N_ + n) * R_ + r) * V_ + v;
    t2o[idx] = a2;
    tSo[idx] = a1;
}

// ---------------------------------------------------------------------------
// k_graphs (slow tier)
// ---------------------------------------------------------------------------
__global__ void k_graphs(const float* __restrict__ t2v, const float* __restrict__ tSv,
                         const float* __restrict__ W4, const float* __restrict__ b4,
                         float* __restrict__ graphs) {
    int kn = blockIdx.x;
    int k = kn / N_, n = kn % N_;
    int kup = (k + 1) % K_;
    __shared__ float F[R_][V_ * V_];
    __shared__ float w4s[O_][R_];
    __shared__ float b4s[O_];
    int tid = threadIdx.x;
    for (int i = tid; i < O_ * R_; i += 256) w4s[i / R_][i % R_] = W4[(size_t)k * O_ * R_ + i];
    if (tid < O_) b4s[tid] = b4[k * O_ + tid];
    for (int idx = tid; idx < R_ * V_ * V_; idx += 256) {
        int r = idx / (V_ * V_), uv = idx % (V_ * V_);
        int u = uv / V_, v = uv % V_;
        int ks = (u < NU_) ? kup : k;
        size_t base = (((size_t)ks * N_ + n) * R_ + r) * V_;
        F[r][uv] = tanhf(tSv[base + u] - t2v[base + v]);
    }
    __syncthreads();
    float* gout = graphs + ((size_t)k * N_ + n) * O_ * (V_ * V_);
    for (int idx = tid; idx < O_ * V_ * V_; idx += 256) {
        int o = idx / (V_ * V_), uv = idx % (V_ * V_);
        float a = b4s[o];
#pragma unroll
        for (int r = 0; r < R_; ++r) a += w4s[o][r] * F[r][uv];
        gout[idx] = a;
    }
}

// ---------------------------------------------------------------------------
// k_graphs2f: fused pool + tvals + F + graphs; ALSO emits Gfrag (tier 1):
//   gfrag[n][o(64)][u(32)][kv(128)] bf16 = graphs + Adj  (pads pre-zeroed
//   by hipMemsetAsync). gfrag may be null (tier 2).
// ---------------------------------------------------------------------------
__global__ void k_graphs2f(const float* __restrict__ pp,
                           const float* __restrict__ W11, const float* __restrict__ b11,
                           const float* __restrict__ W12, const float* __restrict__ b12,
                           const float* __restrict__ W2,  const float* __restrict__ b2,
                           const float* __restrict__ W4,  const float* __restrict__ b4,
                           const float* __restrict__ Adj,
                           float* __restrict__ graphs,
                           unsigned short* __restrict__ gfrag) {
    int bid = blockIdx.x;
    int og = bid & 1;
    int kn = bid >> 1;
    int k = kn / N_, n = kn % N_;
    int kup = (k + 1) % K_;
    __shared__ float poolL[CV];
    __shared__ float t2s[2][R_][V_];
    __shared__ float tSs[2][R_][V_];
    __shared__ float F[R_][V_ * V_];
    __shared__ float w4s[O_][R_];
    __shared__ float b4s[O_];
    int tid = threadIdx.x;
    for (int i = tid; i < O_ * R_; i += 512) w4s[i / R_][i % R_] = W4[(size_t)k * O_ * R_ + i];
    if (tid < O_) b4s[tid] = b4[k * O_ + tid];
    const float* ppn = pp + (size_t)n * 16 * CV;
    for (int i = tid; i < CV; i += 512) {
        float s = 0.f;
#pragma unroll
        for (int tb = 0; tb < 16; ++tb) s += ppn[(size_t)tb * CV + i];
        poolL[i] = s * (1.0f / T_);
    }
    __syncthreads();
    for (int i = tid; i < 2 * R_ * V_; i += 512) {
        int ks = i / (R_ * V_);
        int rem = i - ks * (R_ * V_);
        int r = rem / V_, v = rem - r * V_;
        int kk = ks ? kup : k;
        const float* w2 = W2 + ((size_t)kk * R_ + r) * C_;
        const float* w1 = ((v < NU_) ? W11 : W12) + ((size_t)kk * R_ + r) * C_;
        float a2 = b2[kk * R_ + r];
        float a1 = (v < NU_) ? b11[kk * R_ + r] : b12[kk * R_ + r];
        for (int c = 0; c < C_; ++c) {
            float p = poolL[c * 25 + v];
            a2 += w2[c] * p;
            a1 += w1[c] * p;
        }
        t2s[ks][r][v] = a2;
        tSs[ks][r][v] = a1;
    }
    __syncthreads();
    for (int idx = tid; idx < R_ * V_ * V_; idx += 512) {
        int r = idx / (V_ * V_), uv = idx % (V_ * V_);
        int u = uv / V_, v = uv % V_;
        int ks = (u < NU_) ? 1 : 0;
        F[r][uv] = tanhf(tSs[ks][r][u] - t2s[ks][r][v]);
    }
    __syncthreads();
    float* gout = graphs + ((size_t)k * N_ + n) * O_ * (V_ * V_);
    const int half = O_ * V_ * V_ / 2;
    for (int idx = og * half + tid; idx < (og + 1) * half; idx += 512) {
        int o = idx / (V_ * V_), uv = idx % (V_ * V_);
        float a = b4s[o];
#pragma unroll
        for (int r = 0; r < R_; ++r) a += w4s[o][r] * F[r][uv];
        gout[idx] = a;
        if (gfrag) {
            int u = uv / 25, v = uv - u * 25;
            gfrag[(((size_t)n * 64 + o) * 32 + u) * 128 + k * 25 + v] =
                f2bf(a + Adj[k * 625 + uv]);
        }
    }
}

// ---------------------------------------------------------------------------
// k_biasf: gfrag[n][o][u][125] = sum_k b3[k,o] * sum_v (graphs+Adj)
// ---------------------------------------------------------------------------
__global__ void k_biasf(const float* __restrict__ graphs, const float* __restrict__ Adj,
                        const float* __restrict__ b3, unsigned short* __restrict__ gfrag) {
    int bid = blockIdx.x;               // n*8 + og8
    int n = bid >> 3, og8 = bid & 7;
    int ol = threadIdx.x >> 5, u = threadIdx.x & 31;
    int o = og8 * 8 + ol;
    if (u >= U_) return;
    float s = 0.f;
    for (int k = 0; k < K_; ++k) {
        const float* gp = graphs + (((size_t)k * N_ + n) * O_ + o) * 625 + u * 25;
        const float* ap = Adj + k * 625 + u * 25;
        float t = 0.f;
#pragma unroll
        for (int v = 0; v < V_; ++v) t += gp[v] + ap[v];
        s += t * b3[k * O_ + o];
    }
    gfrag[(((size_t)n * 64 + o) * 32 + u) * 128 + 125] = f2bf(s);
}

// ---------------------------------------------------------------------------
// k_main_fac (tier 1, FACTORED): per block (n, tb 64t, og 2o):
//  stage A: 25 per-v GEMMs -> x2f[o][t][kv] f32, swizzle class
//    swzc(t) = ((t ^ (t>>3)) & 7) << 2 applied by XOR on the dword index
//    (8 classes; t and t+8 differ -> stage-A writes 2-way, stage-B reads
//    uniformly spread — R17's (t&6)<<2 had only 4 coarse classes = 16-way).
//  stage B: out = x2 (A, from LDS via cvtpk) x Gfrag (B, global), K=128;
//    kv=125 carries the bias (x2 col = 1.0). TWO barriers total.
// ---------------------------------------------------------------------------
__global__ __launch_bounds__(256, 2) void k_main_fac(
    const unsigned short* __restrict__ xT3,   // [N][16][200][16][8] bf16 bits
    const unsigned short* __restrict__ gfrag, // [N][64][32][128] bf16
    const float* __restrict__ W3,             // [K][O][C]
    float* __restrict__ out) {

    __shared__ float x2f[2 * 64 * 128];   // 64 KB; idx = o*8192 + t*128 + (kv^swzc(t))

    const int tid = threadIdx.x;
    int raw = blockIdx.x;
    int bid = (raw & 7) * 512 + (raw >> 3);   // XCD swizzle (4096 % 8 == 0)
    const int og = bid & 31;
    const int tb = (bid >> 5) & 3;
    const int n  = bid >> 7;
    const int obase = og * 2;
    const int tgb = tb * 64;
    const int lane = tid & 63;
    const int w = tid >> 6;        // wave = t-tile
    const int lr = lane & 15;
    const int eg = lane >> 4;

    // ---- zero x2f ----
    {
        f32x4 z = {0.f, 0.f, 0.f, 0.f};
        for (int i = tid; i < 2 * 64 * 128 / 4; i += 256) ((f32x4*)x2f)[i] = z;
    }
    __syncthreads();
    // 1.0 column at kv=125 (disjoint from stage A's kv<=124 writes)
    if (tid < 128) {
        int o = tid >> 6, t = tid & 63;
        x2f[o * 8192 + t * 128 + (125 ^ swzc(t))] = 1.0f;
    }

    // ---- W3 B-frags in registers (col = lr -> ncol = k*2+o, elems = c) ----
    bf16x8 wb0, wb1;
    {
        short h0[8] = {0,0,0,0,0,0,0,0}, h1[8] = {0,0,0,0,0,0,0,0};
        if (lr < 10) {
            int k = lr >> 1, o = lr & 1;
            const float* wp = W3 + ((size_t)k * O_ + obase + o) * C_;
#pragma unroll
            for (int e = 0; e < 8; ++e) {
                h0[e] = (short)f2bf(wp[eg * 8 + e]);
                h1[e] = (short)f2bf(wp[32 + eg * 8 + e]);
            }
        }
        wb0 = (bf16x8){h0[0], h0[1], h0[2], h0[3], h0[4], h0[5], h0[6], h0[7]};
        wb1 = (bf16x8){h1[0], h1[1], h1[2], h1[3], h1[4], h1[5], h1[6], h1[7]};
    }

    // ---- stage A: 25 per-v GEMMs (M=16t tile per wave, N=16, K=64) ----
    {
        const int ttb = tb * 4 + w;
        const unsigned short* pA = xT3 + (size_t)n * (T_ * CV)
                                 + ((size_t)(ttb * 200) + eg) * 128 + lr * 8;
        const int kA = lr >> 1, oA = lr & 1;
        const int tl0 = w * 16 + eg * 4;
        for (int v = 0; v < 25; ++v) {
            uint4 a0 = *(const uint4*)(pA + v * 1024);
            uint4 a1 = *(const uint4*)(pA + v * 1024 + 512);
            f32x4 d = {0.f, 0.f, 0.f, 0.f};
            d = __builtin_amdgcn_mfma_f32_16x16x32_bf16(asbf(a0), wb0, d, 0, 0, 0);
            d = __builtin_amdgcn_mfma_f32_16x16x32_bf16(asbf(a1), wb1, d, 0, 0, 0);
            if (lr < 10) {
                int kv = kA * 25 + v;
#pragma unroll
                for (int r2 = 0; r2 < 4; ++r2) {
                    int t = tl0 + r2;
                    x2f[oA * 8192 + t * 128 + (kv ^ swzc(t))] = d[r2];
                }
            }
        }
    }
    __syncthreads();

    // ---- stage B: per wave out tile M=16(t) x N=64(2o x 2nt), K=128 ----
    f32x4 acc[2][2];
#pragma unroll
    for (int o = 0; o < 2; ++o)
#pragma unroll
        for (int nt = 0; nt < 2; ++nt) acc[o][nt] = (f32x4){0.f, 0.f, 0.f, 0.f};

    const unsigned short* gb = gfrag + (((size_t)n * 64 + obase) * 32) * 128;
    const int tB = w * 16 + lr;
    const int swB = swzc(tB);
#pragma unroll
    for (int o = 0; o < 2; ++o) {
        uint4 bf[2][4];
#pragma unroll
        for (int nt = 0; nt < 2; ++nt)
#pragma unroll
            for (int ks = 0; ks < 4; ++ks)
                bf[nt][ks] = *(const uint4*)(gb + (size_t)o * 4096
                                             + (nt * 16 + lr) * 128 + ks * 32 + eg * 8);
#pragma unroll
        for (int ks = 0; ks < 4; ++ks) {
            int c0 = ks * 32 + eg * 8;
            int rowb = o * 8192 + tB * 128;
            f32x4 x0 = *(const f32x4*)&x2f[rowb + (c0 ^ swB)];
            f32x4 x1 = *(const f32x4*)&x2f[rowb + ((c0 + 4) ^ swB)];
            uint4 au;
            au.x = cvtpk(x0[0], x0[1]); au.y = cvtpk(x0[2], x0[3]);
            au.z = cvtpk(x1[0], x1[1]); au.w = cvtpk(x1[2], x1[3]);
            bf16x8 af = asbf(au);
            acc[o][0] = __builtin_amdgcn_mfma_f32_16x16x32_bf16(af, asbf(bf[0][ks]), acc[o][0], 0, 0, 0);
            acc[o][1] = __builtin_amdgcn_mfma_f32_16x16x32_bf16(af, asbf(bf[1][ks]), acc[o][1], 0, 0, 0);
        }
    }

    // ---- epilogue: C/D col = lr (u), rows = eg*4+r2 (t-in-tile) ----
#pragma unroll
    for (int o = 0; o < 2; ++o) {
        float* ob = out + ((size_t)n * O_ + obase + o) * T_ * V_;
#pragma unroll
        for (int nt = 0; nt < 2; ++nt) {
            int u = nt * 16 + lr;
            if (u < U_) {
#pragma unroll
                for (int r2 = 0; r2 < 4; ++r2) {
                    int t = tgb + w * 16 + eg * 4 + r2;
                    ob[(size_t)t * V_ + u] = acc[o][nt][r2];
                }
            }
        }
    }
}

// ---------------------------------------------------------------------------
// k_main_fast2 (tier 2 = proven R16 kernel)
// ---------------------------------------------------------------------------
__global__ __launch_bounds__(256, 4) void k_main_fast2(
    const unsigned short* __restrict__ xT3,
    const float* __restrict__ graphs,
    const float* __restrict__ Adj,
    const float* __restrict__ W3,
    const float* __restrict__ b3,
    float* __restrict__ out) {

    __shared__ unsigned short Hs[4][4][NB][8];
    __shared__ uint2 Gbf4[OG * 625];
    __shared__ unsigned short Gbf1[OG * 625];
    __shared__ unsigned short W3kmh[K_ * OG * C_];
    __shared__ float biasS[NB];

    const int tid = threadIdx.x;
    int bid = blockIdx.x;
    bid = (bid & 7) * 128 + (bid >> 3);
    const int obase = (bid & 31) * OG;
    const int n = bid >> 5;
    const int lane = tid & 63;
    const int wv_ = tid >> 6;

    const size_t kstride = (size_t)N_ * O_ * 625;
    for (int i = tid; i < OG * 625; i += 256) {
        int o = i / 625, uv = i - o * 625;
        int u = uv / 25, v = uv - u * 25;
        size_t gb = ((size_t)n * O_ + obase + o) * 625 + uv;
        float g0 = graphs[gb]               + Adj[uv];
        float g1 = graphs[gb + kstride]     + Adj[625 + uv];
        float g2 = graphs[gb + 2 * kstride] + Adj[1250 + uv];
        float g3 = graphs[gb + 3 * kstride] + Adj[1875 + uv];
        float g4 = graphs[gb + 4 * kstride] + Adj[2500 + uv];
        int idx = o * 625 + v * 25 + u;
        uint2 w; w.x = pk2(g0, g1); w.y = pk2(g2, g3);
        Gbf4[idx] = w;
        Gbf1[idx] = f2bf(g4);
    }
    for (int i = tid; i < K_ * OG * C_; i += 256) {
        int k = i / (OG * C_);
        int rem = i - k * (OG * C_);
        int o = rem >> 6, c = rem & 63;
        W3kmh[(k * OG + o) * C_ + c] = f2bf(W3[((size_t)k * O_ + obase + o) * C_ + c]);
    }
    __syncthreads();

    if (tid < NB) {
        int o = tid >> 5, u = tid & 31;
        float bv = 0.f;
        if (u < U_) {
            float s0 = 0.f, s1 = 0.f, s2 = 0.f, s3 = 0.f, s4 = 0.f;
            for (int v = 0; v < V_; ++v) {
                int idx = o * 625 + v * 25 + u;
                uint2 w = Gbf4[idx];
                s0 += bf_lo(w.x); s1 += bf_hi(w.x);
                s2 += bf_lo(w.y); s3 += bf_hi(w.y);
                s4 += bf2f(Gbf1[idx]);
            }
            bv = s0 * b3[0 * O_ + obase + o] + s1 * b3[1 * O_ + obase + o]
               + s2 * b3[2 * O_ + obase + o] + s3 * b3[3 * O_ + obase + o]
               + s4 * b3[4 * O_ + obase + o];
        }
        biasS[tid] = bv;
    }

    const int sl = wv_;
    const int hncol = lane;
    const int ho = hncol >> 5;
    const int hu = hncol & 31;
    const uint2* gp4 = &Gbf4[ho * 625 + hu];
    const unsigned short* gp1 = &Gbf1[ho * 625 + hu];
    const unsigned short* wbh = &W3kmh[ho * C_ + sl * 8];
    char* hwb = (char*)&Hs[0][sl][hncol][0];

    auto h_form = [&](char* hwp, const int parOff, f32x4 g, float g5) {
        float gk[5] = {g[0], g[1], g[2], g[3], g5};
        float h0 = 0.f, h1 = 0.f, h2 = 0.f, h3 = 0.f;
        float h4 = 0.f, h5 = 0.f, h6 = 0.f, h7 = 0.f;
#pragma unroll
        for (int k = 0; k < K_; ++k) {
            uint4 wk = *(const uint4*)(wbh + parOff + k * (OG * C_));
            float gv_ = gk[k];
            h0 += bf_lo(wk.x) * gv_; h1 += bf_hi(wk.x) * gv_;
            h2 += bf_lo(wk.y) * gv_; h3 += bf_hi(wk.y) * gv_;
            h4 += bf_lo(wk.z) * gv_; h5 += bf_hi(wk.z) * gv_;
            h6 += bf_lo(wk.w) * gv_; h7 += bf_hi(wk.w) * gv_;
        }
        uint4 hv;
        hv.x = cvtpk(h0, h1); hv.y = cvtpk(h2, h3);
        hv.z = cvtpk(h4, h5); hv.w = cvtpk(h6, h7);
        *(uint4*)hwp = hv;
    };
    auto ld_g = [&](int voff25, f32x4& g, float& g5) {
        if (hu < U_) {
            uint2 gw = gp4[voff25];
            g[0] = bf_lo(gw.x); g[1] = bf_hi(gw.x);
            g[2] = bf_lo(gw.y); g[3] = bf_hi(gw.y);
            g5 = bf2f(gp1[voff25]);
        } else { g = (f32x4){0.f, 0.f, 0.f, 0.f}; g5 = 0.f; }
    };

    const int wm = wv_;
    const int lr = lane & 15;
    const int eg = lane >> 4;

    f32x4 acc[4][4];
#pragma unroll
    for (int mt = 0; mt < 4; ++mt)
#pragma unroll
        for (int nt = 0; nt < 4; ++nt) acc[mt][nt] = (f32x4){0.f, 0.f, 0.f, 0.f};

    const unsigned short* An = xT3 + (size_t)n * (T_ * CV);
    const unsigned short* a0 = An + ((size_t)((wm * 4 + 0) * 200 + eg)) * 128 + lr * 8;
    const unsigned short* a1 = a0 + 200 * 128;
    const unsigned short* a2 = a0 + 400 * 128;
    const unsigned short* a3 = a0 + 600 * 128;
    const char* hrb = (const char*)&Hs[0][eg][lr][0];

    auto consume = [&](int sub, int bufb) {
        uint4 av0 = *(const uint4*)(a0 + sub);
        uint4 av1 = *(const uint4*)(a1 + sub);
        uint4 av2 = *(const uint4*)(a2 + sub);
        uint4 av3 = *(const uint4*)(a3 + sub);
        bf16x8 b[4];
#pragma unroll
        for (int nt = 0; nt < 4; ++nt)
            b[nt] = *(const bf16x8*)(hrb + bufb + nt * 256);
        __builtin_amdgcn_s_setprio(1);
        union { uint4 u; bf16x8 h; } c0, c1, c2, c3;
        c0.u = av0; c1.u = av1; c2.u = av2; c3.u = av3;
#pragma unroll
        for (int nt = 0; nt < 4; ++nt) acc[0][nt] = __builtin_amdgcn_mfma_f32_16x16x32_bf16(c0.h, b[nt], acc[0][nt], 0, 0, 0);
#pragma unroll
        for (int nt = 0; nt < 4; ++nt) acc[1][nt] = __builtin_amdgcn_mfma_f32_16x16x32_bf16(c1.h, b[nt], acc[1][nt], 0, 0, 0);
#pragma unroll
        for (int nt = 0; nt < 4; ++nt) acc[2][nt] = __builtin_amdgcn_mfma_f32_16x16x32_bf16(c2.h, b[nt], acc[2][nt], 0, 0, 0);
#pragma unroll
        for (int nt = 0; nt < 4; ++nt) acc[3][nt] = __builtin_amdgcn_mfma_f32_16x16x32_bf16(c3.h, b[nt], acc[3][nt], 0, 0, 0);
        __builtin_amdgcn_s_setprio(0);
    };

    f32x4 gv; float gv5;
    ld_g(0, gv, gv5);
    h_form(hwb, 0, gv, gv5);
    h_form(hwb + 4096, 32, gv, gv5);
    __syncthreads();

    for (int kc2 = 0; kc2 < 25; ++kc2) {
        const int rb = (kc2 & 1) * 8192;
        const int wb = 8192 - rb;
        if (kc2 + 1 < 25) ld_g((kc2 + 1) * 25, gv, gv5);
        consume(0, rb);
        consume(512, rb + 4096);
        if (kc2 + 1 < 25) {
            h_form(hwb + wb, 0, gv, gv5);
            h_form(hwb + wb + 4096, 32, gv, gv5);
        }
        __syncthreads();
        a0 += 1024; a1 += 1024; a2 += 1024; a3 += 1024;
    }

#pragma unroll
    for (int nt = 0; nt < 4; ++nt) {
        int ncol = nt * 16 + lr;
        int ol = ncol >> 5;
        int u  = ncol & 31;
        if (u < U_) {
            float bv = biasS[ncol];
            float* ob = out + ((size_t)n * O_ + obase + ol) * T_ * V_ + u;
#pragma unroll
            for (int mt = 0; mt < 4; ++mt) {
                int t0 = wm * 64 + mt * 16 + eg * 4;
#pragma unroll
                for (int r2 = 0; r2 < 4; ++r2)
                    ob[(size_t)(t0 + r2) * V_] = acc[mt][nt][r2] + bv;
            }
        }
    }
}

// ---------------------------------------------------------------------------
// k_main_slow (tier 3, proven R2 path)
// ---------------------------------------------------------------------------
#define OB 4
#define TB 64
__global__ __launch_bounds__(256, 1) void k_main_slow(
    const float* __restrict__ x, const float* __restrict__ graphs,
    const float* __restrict__ A, const float* __restrict__ W3,
    const float* __restrict__ b3, float* __restrict__ out) {
    int bid = blockIdx.x;
    int tb = bid & 3;
    int ob = (bid >> 2) & 15;
    int n  = bid >> 6;
    int tid = threadIdx.x;
    int ol = tid >> 6;
    int tl = tid & 63;
    int t = tb * TB + tl;
    int o = ob * OB + ol;

    __shared__ float Gs[K_][OB][V_][28];
    __shared__ float W3s[K_][OB][C_];
    __shared__ float b3s[K_][OB];

    for (int i = tid; i < K_ * OB * V_ * V_; i += 256) {
        int k   = i / (OB * V_ * V_);
        int rem = i % (OB * V_ * V_);
        int oo  = rem / (V_ * V_);
        int uv  = rem % (V_ * V_);
        Gs[k][oo][uv / V_][uv % V_] =
            graphs[(((size_t)k * N_ + n) * O_ + ob * OB + oo) * (V_ * V_) + uv]
            + A[k * V_ * V_ + uv];
    }
    for (int i = tid; i < K_ * OB * C_; i += 256) {
        int k   = i / (OB * C_);
        int rem = i % (OB * C_);
        int oo  = rem / C_, c = rem % C_;
        W3s[k][oo][c] = W3[((size_t)k * O_ + ob * OB + oo) * C_ + c];
    }
    if (tid < K_ * OB) b3s[tid / OB][tid % OB] = b3[(tid / OB) * O_ + ob * OB + tid % OB];
    __syncthreads();

    float x2[K_][V_];
#pragma unroll
    for (int k = 0; k < K_; ++k)
#pragma unroll
        for (int v = 0; v < V_; ++v) x2[k][v] = b3s[k][ol];

    const float* xb = x + ((size_t)n * C_ * T_ + t) * V_;
    for (int c = 0; c < C_; ++c) {
        const float* p = xb + (size_t)c * T_ * V_;
        float xv[V_];
#pragma unroll
        for (int v = 0; v < V_; ++v) xv[v] = p[v];
#pragma unroll
        for (int k = 0; k < K_; ++k) {
            float w = W3s[k][ol][c];
#pragma unroll
            for (int v = 0; v < V_; ++v) x2[k][v] += w * xv[v];
        }
    }

    float acc[V_];
#pragma unroll
    for (int u = 0; u < V_; ++u) acc[u] = 0.0f;
#pragma unroll
    for (int k = 0; k < K_; ++k) {
#pragma unroll
        for (int u = 0; u < V_; ++u) {
            const float* gr = &Gs[k][ol][u][0];
            float s = 0.0f;
#pragma unroll
            for (int v = 0; v < V_; ++v) s += gr[v] * x2[k][v];
            acc[u] += s;
        }
    }
    float* po = out + (((size_t)n * O_ + o) * T_ + t) * V_;
#pragma unroll
    for (int u = 0; u < V_; ++u) po[u] = acc[u];
}

// ---------------------------------------------------------------------------
extern "C" void kernel_launch(void* const* d_in, const int* in_sizes, int n_in,
                              void* d_out, int out_size, void* d_ws, size_t ws_size,
                              hipStream_t stream) {
    const float* x   = (const float*)d_in[0];
    const float* A   = (const float*)d_in[1];
    const float* W11 = (const float*)d_in[2];
    const float* b11 = (const float*)d_in[3];
    const float* W12 = (const float*)d_in[4];
    const float* b12 = (const float*)d_in[5];
    const float* W2  = (const float*)d_in[6];
    const float* b2  = (const float*)d_in[7];
    const float* W3  = (const float*)d_in[8];
    const float* b3  = (const float*)d_in[9];
    const float* W4  = (const float*)d_in[10];
    const float* b4  = (const float*)d_in[11];

    float* out    = (float*)d_out;
    float* graphs = out + OUT_ELEMS;   // second tuple element

    const size_t xT_bytes = sizeof(unsigned short) * (size_t)N_ * T_ * CV;  // 26.2 MB
    const size_t pp_bytes = sizeof(float) * (size_t)N_ * 16 * CV;           //  3.3 MB
    const size_t gf_bytes = sizeof(unsigned short) * (size_t)N_ * 64 * 32 * 128; // 16.8 MB
    const size_t hdr      = (size_t)(1 << 20);
    const bool tier1 = (ws_size >= hdr + xT_bytes + pp_bytes + gf_bytes);
    const bool tier2 = (ws_size >= hdr + xT_bytes + pp_bytes);

    const size_t poolElems = (size_t)N_ * C_ * V_;
    const size_t tElems    = (size_t)K_ * N_ * R_ * V_;
    const size_t slowNeed  = (poolElems + 2 * tElems) * sizeof(float);

    float* scratch = (tier2 || ws_size >= slowNeed) ? (float*)d_ws : out;
    float* pool = scratch;
    float* t2v  = scratch + poolElems;
    float* tSv  = t2v + tElems;
    unsigned short* xT3 = (unsigned short*)((char*)d_ws + hdr);
    float* pp = (float*)((char*)d_ws + hdr + xT_bytes);
    unsigned short* gfrag = (unsigned short*)((char*)d_ws + hdr + xT_bytes + pp_bytes);

    if (tier1) {
        k_xcast<<<N_ * 16, 256, 0, stream>>>(x, xT3, pp);
        hipMemsetAsync(gfrag, 0, gf_bytes, stream);
        k_graphs2f<<<K_ * N_ * 2, 512, 0, stream>>>(pp, W11, b11, W12, b12, W2, b2, W4, b4, A, graphs, gfrag);
        k_biasf<<<N_ * 8, 256, 0, stream>>>(graphs, A, b3, gfrag);
        k_main_fac<<<N_ * 4 * 32, 256, 0, stream>>>(xT3, gfrag, W3, out);
    } else if (tier2) {
        k_xcast<<<N_ * 16, 256, 0, stream>>>(x, xT3, pp);
        k_graphs2f<<<K_ * N_ * 2, 512, 0, stream>>>(pp, W11, b11, W12, b12, W2, b2, W4, b4, A, graphs, (unsigned short*)nullptr);
        k_main_fast2<<<N_ * 32, 256, 0, stream>>>(xT3, graphs, A, W3, b3, out);
    } else {
        k_pool  <<<N_ * C_, 256, 0, stream>>>(x, pool);
        k_tvals <<<K_ * N_, 256, 0, stream>>>(pool, W11, b11, W12, b12, W2, b2, t2v, tSv);
        k_graphs<<<K_ * N_, 256, 0, stream>>>(t2v, tSv, W4, b4, graphs);
        k_main_slow<<<N_ * (O_ / OB) * 4, 256, 0, stream>>>(x, graphs, A, W3, b3, out);
    }
}

// Round 19
// 125.714 us; speedup vs baseline: 1.3095x; 1.3095x over previous
//
#include <hip/hip_runtime.h>
#include <cstdint>
#include <cstddef>

#define N_  32
#define C_  64
#define T_  256
#define V_  25
#define R_  8
#define O_  64
#define K_  5
#define NU_ 17
#define U_  25
#define CV  (C_ * V_)        // 1600
#define OG  2                // o's per block (tier-1 and tier-2 k_main)
#define NB  (OG * 32)        // 64 ncols (tier-2)

#define OUT_ELEMS ((size_t)N_ * O_ * T_ * V_)   // 13,107,200

typedef __attribute__((ext_vector_type(8))) short bf16x8;
typedef __attribute__((ext_vector_type(4))) float f32x4;

static __device__ __forceinline__ unsigned short f2bf(float f) {
    union { float f; unsigned u; } c; c.f = f;
    return (unsigned short)((c.u + 0x8000u) >> 16);
}
static __device__ __forceinline__ float bf2f(unsigned short h) {
    union { unsigned u; float f; } c; c.u = ((unsigned)h) << 16; return c.f;
}
static __device__ __forceinline__ float bf_lo(unsigned d) {
    union { unsigned u; float f; } c; c.u = d << 16; return c.f;
}
static __device__ __forceinline__ float bf_hi(unsigned d) {
    union { unsigned u; float f; } c; c.u = d & 0xFFFF0000u; return c.f;
}
static __device__ __forceinline__ unsigned pk2(float a, float b) {
    union { float f; unsigned u; } ca, cb; ca.f = a; cb.f = b;
    return ((ca.u + 0x8000u) >> 16) | ((cb.u + 0x8000u) & 0xFFFF0000u);
}
static __device__ __forceinline__ unsigned cvtpk(float a, float b) {
    unsigned r;
    asm("v_cvt_pk_bf16_f32 %0, %1, %2" : "=v"(r) : "v"(a), "v"(b));
    return r;
}
static __device__ __forceinline__ bf16x8 asbf(uint4 u) {
    union { uint4 u; bf16x8 h; } c; c.u = u; return c.h;
}
// x2h swizzle class in USHORT units (16B slot = 8 ushorts): bits 3-5.
static __device__ __forceinline__ int clsw(int t) {
    return ((t ^ (t >> 3)) & 7) << 3;
}

// ---------------------------------------------------------------------------
// k_xcast: fragment-native xT3 with cv' = v*64+c ordering:
//   xT3[n][tt(16)][s'(200)][tl(16)][ke(8)],  s' = v*8 + c/8, ke = c&7.
// ---------------------------------------------------------------------------
__global__ void k_xcast(const float* __restrict__ x, unsigned short* __restrict__ xT3,
                        float* __restrict__ pp) {
    __shared__ unsigned short tile[C_][408];   // [c][t*25+v], row 816 B
    int bid = blockIdx.x;
    int n = bid >> 4, tb = bid & 15;
    int tid = threadIdx.x;
    const float* xb = x + (size_t)n * C_ * T_ * V_ + tb * 400;
#pragma unroll
    for (int it = 0; it < 25; ++it) {
        int i = it * 256 + tid;          // < 6400
        int c = i / 100, q = i - c * 100;
        float4 v4 = *(const float4*)(xb + (size_t)c * (T_ * V_) + q * 4);
        uint2 w;
        w.x = pk2(v4.x, v4.y);
        w.y = pk2(v4.z, v4.w);
        *(uint2*)&tile[c][q * 4] = w;
    }
    __syncthreads();
    unsigned short* dstb = xT3 + ((size_t)(n * 16 + tb) * 200) * 128;
    for (int i = tid; i < 200 * 16; i += 256) {
        int sp = i >> 4, tl = i & 15;
        int v = sp >> 3, c0 = (sp & 7) * 8;
        unsigned short h[8];
#pragma unroll
        for (int j = 0; j < 8; ++j) h[j] = tile[c0 + j][tl * 25 + v];
        uint4 pk;
        pk.x = (unsigned)h[0] | ((unsigned)h[1] << 16);
        pk.y = (unsigned)h[2] | ((unsigned)h[3] << 16);
        pk.z = (unsigned)h[4] | ((unsigned)h[5] << 16);
        pk.w = (unsigned)h[6] | ((unsigned)h[7] << 16);
        *(uint4*)(dstb + (size_t)sp * 128 + tl * 8) = pk;
    }
    float* ppd = pp + ((size_t)n * 16 + tb) * CV;
    for (int e = tid; e < CV; e += 256) {
        int c = e / 25, v = e - c * 25;
        float s = 0.f;
#pragma unroll
        for (int t = 0; t < 16; ++t) s += bf2f(tile[c][t * 25 + v]);
        ppd[e] = s;
    }
}

// classic pool (slow tier)
__global__ void k_pool(const float* __restrict__ x, float* __restrict__ pool) {
    int nc = blockIdx.x;
    int t  = threadIdx.x;
    const float* px = x + ((size_t)nc * T_ + t) * V_;
    float acc[V_];
#pragma unroll
    for (int v = 0; v < V_; ++v) acc[v] = px[v];
#pragma unroll
    for (int off = 32; off > 0; off >>= 1) {
#pragma unroll
        for (int v = 0; v < V_; ++v) acc[v] += __shfl_down(acc[v], off, 64);
    }
    __shared__ float sm[4][V_];
    int wave = t >> 6, lane = t & 63;
    if (lane == 0) {
#pragma unroll
        for (int v = 0; v < V_; ++v) sm[wave][v] = acc[v];
    }
    __syncthreads();
    if (t < V_) {
        float s = sm[0][t] + sm[1][t] + sm[2][t] + sm[3][t];
        pool[(size_t)nc * V_ + t] = s * (1.0f / T_);
    }
}

// ---------------------------------------------------------------------------
// k_tvals (slow tier only)
// ---------------------------------------------------------------------------
__global__ void k_tvals(const float* __restrict__ pool,
                        const float* __restrict__ W11, const float* __restrict__ b11,
                        const float* __restrict__ W12, const float* __restrict__ b12,
                        const float* __restrict__ W2,  const float* __restrict__ b2,
                        float* __restrict__ t2o, float* __restrict__ tSo) {
    int kn = blockIdx.x;
    int k = kn / N_, n = kn % N_;
    int tid = threadIdx.x;
    int r = tid >> 5, v = tid & 31;
    if (v >= V_) return;
    const float* pp = pool + (size_t)n * C_ * V_ + v;
    const float* w2 = W2 + ((size_t)k * R_ + r) * C_;
    const float* w1 = ((v < NU_) ? W11 : W12) + ((size_t)k * R_ + r) * C_;
    float a2 = b2[k * R_ + r];
    float a1 = (v < NU_) ? b11[k * R_ + r] : b12[k * R_ + r];
    for (int c = 0; c < C_; ++c) {
        float p = pp[(size_t)c * V_];
        a2 += w2[c] * p;
        a1 += w1[c] * p;
    }
    size_t idx = (((size_t)k * N_ + n) * R_ + r) * V_ + v;
    t2o[idx] = a2;
    tSo[idx] = a1;
}

// ---------------------------------------------------------------------------
// k_graphs (slow tier)
// ---------------------------------------------------------------------------
__global__ void k_graphs(const float* __restrict__ t2v, const float* __restrict__ tSv,
                         const float* __restrict__ W4, const float* __restrict__ b4,
                         float* __restrict__ graphs) {
    int kn = blockIdx.x;
    int k = kn / N_, n = kn % N_;
    int kup = (k + 1) % K_;
    __shared__ float F[R_][V_ * V_];
    __shared__ float w4s[O_][R_];
    __shared__ float b4s[O_];
    int tid = threadIdx.x;
    for (int i = tid; i < O_ * R_; i += 256) w4s[i / R_][i % R_] = W4[(size_t)k * O_ * R_ + i];
    if (tid < O_) b4s[tid] = b4[k * O_ + tid];
    for (int idx = tid; idx < R_ * V_ * V_; idx += 256) {
        int r = idx / (V_ * V_), uv = idx % (V_ * V_);
        int u = uv / V_, v = uv % V_;
        int ks = (u < NU_) ? kup : k;
        size_t base = (((size_t)ks * N_ + n) * R_ + r) * V_;
        F[r][uv] = tanhf(tSv[base + u] - t2v[base + v]);
    }
    __syncthreads();
    float* gout = graphs + ((size_t)k * N_ + n) * O_ * (V_ * V_);
    for (int idx = tid; idx < O_ * V_ * V_; idx += 256) {
        int o = idx / (V_ * V_), uv = idx % (V_ * V_);
        float a = b4s[o];
#pragma unroll
        for (int r = 0; r < R_; ++r) a += w4s[o][r] * F[r][uv];
        gout[idx] = a;
    }
}

// ---------------------------------------------------------------------------
// k_graphs2f: fused pool + tvals + F + graphs; ALSO emits Gfrag (tier 1):
//   gfrag[n][o(64)][u(32)][kv(128)] bf16 = graphs + Adj.
//   Pads (u>=25 rows, kv>=126) are left as-is: u-pad outputs are masked at
//   the store, kv-pads multiply x2h zeros. gfrag may be null (tier 2).
// ---------------------------------------------------------------------------
__global__ void k_graphs2f(const float* __restrict__ pp,
                           const float* __restrict__ W11, const float* __restrict__ b11,
                           const float* __restrict__ W12, const float* __restrict__ b12,
                           const float* __restrict__ W2,  const float* __restrict__ b2,
                           const float* __restrict__ W4,  const float* __restrict__ b4,
                           const float* __restrict__ Adj,
                           float* __restrict__ graphs,
                           unsigned short* __restrict__ gfrag) {
    int bid = blockIdx.x;
    int og = bid & 1;
    int kn = bid >> 1;
    int k = kn / N_, n = kn % N_;
    int kup = (k + 1) % K_;
    __shared__ float poolL[CV];
    __shared__ float t2s[2][R_][V_];
    __shared__ float tSs[2][R_][V_];
    __shared__ float F[R_][V_ * V_];
    __shared__ float w4s[O_][R_];
    __shared__ float b4s[O_];
    int tid = threadIdx.x;
    for (int i = tid; i < O_ * R_; i += 512) w4s[i / R_][i % R_] = W4[(size_t)k * O_ * R_ + i];
    if (tid < O_) b4s[tid] = b4[k * O_ + tid];
    const float* ppn = pp + (size_t)n * 16 * CV;
    for (int i = tid; i < CV; i += 512) {
        float s = 0.f;
#pragma unroll
        for (int tb = 0; tb < 16; ++tb) s += ppn[(size_t)tb * CV + i];
        poolL[i] = s * (1.0f / T_);
    }
    __syncthreads();
    for (int i = tid; i < 2 * R_ * V_; i += 512) {
        int ks = i / (R_ * V_);
        int rem = i - ks * (R_ * V_);
        int r = rem / V_, v = rem - r * V_;
        int kk = ks ? kup : k;
        const float* w2 = W2 + ((size_t)kk * R_ + r) * C_;
        const float* w1 = ((v < NU_) ? W11 : W12) + ((size_t)kk * R_ + r) * C_;
        float a2 = b2[kk * R_ + r];
        float a1 = (v < NU_) ? b11[kk * R_ + r] : b12[kk * R_ + r];
        for (int c = 0; c < C_; ++c) {
            float p = poolL[c * 25 + v];
            a2 += w2[c] * p;
            a1 += w1[c] * p;
        }
        t2s[ks][r][v] = a2;
        tSs[ks][r][v] = a1;
    }
    __syncthreads();
    for (int idx = tid; idx < R_ * V_ * V_; idx += 512) {
        int r = idx / (V_ * V_), uv = idx % (V_ * V_);
        int u = uv / V_, v = uv % V_;
        int ks = (u < NU_) ? 1 : 0;
        F[r][uv] = tanhf(tSs[ks][r][u] - t2s[ks][r][v]);
    }
    __syncthreads();
    float* gout = graphs + ((size_t)k * N_ + n) * O_ * (V_ * V_);
    const int half = O_ * V_ * V_ / 2;
    for (int idx = og * half + tid; idx < (og + 1) * half; idx += 512) {
        int o = idx / (V_ * V_), uv = idx % (V_ * V_);
        float a = b4s[o];
#pragma unroll
        for (int r = 0; r < R_; ++r) a += w4s[o][r] * F[r][uv];
        gout[idx] = a;
        if (gfrag) {
            int u = uv / 25, v = uv - u * 25;
            gfrag[(((size_t)n * 64 + o) * 32 + u) * 128 + k * 25 + v] =
                f2bf(a + Adj[k * 625 + uv]);
        }
    }
}

// ---------------------------------------------------------------------------
// k_biasf: gfrag[n][o][u][125] = sum_k b3[k,o] * sum_v (graphs+Adj)
// ---------------------------------------------------------------------------
__global__ void k_biasf(const float* __restrict__ graphs, const float* __restrict__ Adj,
                        const float* __restrict__ b3, unsigned short* __restrict__ gfrag) {
    int bid = blockIdx.x;               // n*8 + og8
    int n = bid >> 3, og8 = bid & 7;
    int ol = threadIdx.x >> 5, u = threadIdx.x & 31;
    int o = og8 * 8 + ol;
    if (u >= U_) return;
    float s = 0.f;
    for (int k = 0; k < K_; ++k) {
        const float* gp = graphs + (((size_t)k * N_ + n) * O_ + o) * 625 + u * 25;
        const float* ap = Adj + k * 625 + u * 25;
        float t = 0.f;
#pragma unroll
        for (int v = 0; v < V_; ++v) t += gp[v] + ap[v];
        s += t * b3[k * O_ + o];
    }
    gfrag[(((size_t)n * 64 + o) * 32 + u) * 128 + 125] = f2bf(s);
}

// ---------------------------------------------------------------------------
// k_main_fac (tier 1, FACTORED, WAVE-LOCAL, ZERO BARRIERS):
//  Key property: stage-B's wave w reads only t in [w*16, w*16+16) — exactly
//  the rows stage-A's wave w writes. Same-wave ds ordering (lgkmcnt) makes
//  block barriers unnecessary.
//  stage A: 25 per-v GEMMs (full #pragma unroll -> deep load pipelining),
//    x2 stored BF16: x2h[o][t][kv ^ clsw(t)], rows 256B, 32 KB total.
//  stage B: out = x2h (A-frag, direct bf16x8) x gfrag (B, global), K=128;
//    kv=125 carries bias (x2 col = 1.0), kv 126/127 zeroed per-wave.
//  4 blocks/CU (32 KB LDS), 4 waves/SIMD. WRITE_SIZE = spill watchdog.
// ---------------------------------------------------------------------------
__global__ __launch_bounds__(256, 4) void k_main_fac(
    const unsigned short* __restrict__ xT3,   // [N][16][200][16][8] bf16 bits
    const unsigned short* __restrict__ gfrag, // [N][64][32][128] bf16
    const float* __restrict__ W3,             // [K][O][C]
    float* __restrict__ out) {

    __shared__ unsigned short x2h[2 * 64 * 128];   // 32 KB

    const int tid = threadIdx.x;
    int raw = blockIdx.x;
    int bid = (raw & 7) * 512 + (raw >> 3);   // XCD swizzle (4096 % 8 == 0)
    const int og = bid & 31;
    const int tb = (bid >> 5) & 3;
    const int n  = bid >> 7;
    const int obase = og * 2;
    const int tgb = tb * 64;
    const int lane = tid & 63;
    const int w = tid >> 6;        // wave = t-tile
    const int lr = lane & 15;
    const int eg = lane >> 4;

    // ---- W3 B-frags in registers (col = lr -> ncol = k*2+o, elems = c) ----
    bf16x8 wb0, wb1;
    {
        short h0[8] = {0,0,0,0,0,0,0,0}, h1[8] = {0,0,0,0,0,0,0,0};
        if (lr < 10) {
            int k = lr >> 1, o = lr & 1;
            const float* wp = W3 + ((size_t)k * O_ + obase + o) * C_;
#pragma unroll
            for (int e = 0; e < 8; ++e) {
                h0[e] = (short)f2bf(wp[eg * 8 + e]);
                h1[e] = (short)f2bf(wp[32 + eg * 8 + e]);
            }
        }
        wb0 = (bf16x8){h0[0], h0[1], h0[2], h0[3], h0[4], h0[5], h0[6], h0[7]};
        wb1 = (bf16x8){h1[0], h1[1], h1[2], h1[3], h1[4], h1[5], h1[6], h1[7]};
    }

    // ---- per-wave pad init: lanes 0..31 cover (o, 16 wave-local t's) ----
    if (lane < 32) {
        int o = lane >> 4, t = w * 16 + (lane & 15);
        int cls = clsw(t);
        int rowb = o * 8192 + t * 128;
        x2h[rowb + (125 ^ cls)] = 0x3F80;   // 1.0 in bf16 (bias column)
        x2h[rowb + (126 ^ cls)] = 0;
        x2h[rowb + (127 ^ cls)] = 0;
    }

    // ---- stage A: 25 per-v GEMMs, fully unrolled (deep load pipelining) ----
    {
        const int ttb = tb * 4 + w;
        const unsigned short* pA = xT3 + (size_t)n * (T_ * CV)
                                 + ((size_t)(ttb * 200) + eg) * 128 + lr * 8;
        const int kA = lr >> 1, oA = lr & 1;
        const int tl0 = w * 16 + eg * 4;
#pragma unroll
        for (int v = 0; v < 25; ++v) {
            uint4 a0 = *(const uint4*)(pA + v * 1024);
            uint4 a1 = *(const uint4*)(pA + v * 1024 + 512);
            f32x4 d = {0.f, 0.f, 0.f, 0.f};
            d = __builtin_amdgcn_mfma_f32_16x16x32_bf16(asbf(a0), wb0, d, 0, 0, 0);
            d = __builtin_amdgcn_mfma_f32_16x16x32_bf16(asbf(a1), wb1, d, 0, 0, 0);
            if (lr < 10) {
                int kv = kA * 25 + v;
#pragma unroll
                for (int r2 = 0; r2 < 4; ++r2) {
                    int t = tl0 + r2;
                    x2h[oA * 8192 + t * 128 + (kv ^ clsw(t))] = f2bf(d[r2]);
                }
            }
        }
    }
    // NO barrier: stage-B reads are wave-local (same-wave lgkmcnt ordering).

    // ---- stage B: per wave M=16(t) x N=64(2o x 2nt), K=128 ----
    f32x4 acc[2][2];
#pragma unroll
    for (int o = 0; o < 2; ++o)
#pragma unroll
        for (int nt = 0; nt < 2; ++nt) acc[o][nt] = (f32x4){0.f, 0.f, 0.f, 0.f};

    const unsigned short* gb = gfrag + (((size_t)n * 64 + obase) * 32) * 128;
    const int tB = w * 16 + lr;
    const int clsB = clsw(tB);
    const int rowB = tB * 128;
#pragma unroll
    for (int o = 0; o < 2; ++o) {
#pragma unroll
        for (int ks = 0; ks < 4; ++ks) {
            const int kv0 = ks * 32 + eg * 8;
            bf16x8 af = *(const bf16x8*)&x2h[o * 8192 + rowB + (kv0 ^ clsB)];
            uint4 b0 = *(const uint4*)(gb + (size_t)o * 4096 + (0 * 16 + lr) * 128 + kv0);
            uint4 b1 = *(const uint4*)(gb + (size_t)o * 4096 + (1 * 16 + lr) * 128 + kv0);
            acc[o][0] = __builtin_amdgcn_mfma_f32_16x16x32_bf16(af, asbf(b0), acc[o][0], 0, 0, 0);
            acc[o][1] = __builtin_amdgcn_mfma_f32_16x16x32_bf16(af, asbf(b1), acc[o][1], 0, 0, 0);
        }
    }

    // ---- epilogue: C/D col = lr (u), rows = eg*4+r2 (t-in-tile) ----
#pragma unroll
    for (int o = 0; o < 2; ++o) {
        float* ob = out + ((size_t)n * O_ + obase + o) * T_ * V_;
#pragma unroll
        for (int nt = 0; nt < 2; ++nt) {
            int u = nt * 16 + lr;
            if (u < U_) {
#pragma unroll
                for (int r2 = 0; r2 < 4; ++r2) {
                    int t = tgb + w * 16 + eg * 4 + r2;
                    ob[(size_t)t * V_ + u] = acc[o][nt][r2];
                }
            }
        }
    }
}

// ---------------------------------------------------------------------------
// k_main_fast2 (tier 2 = proven R16 kernel)
// ---------------------------------------------------------------------------
__global__ __launch_bounds__(256, 4) void k_main_fast2(
    const unsigned short* __restrict__ xT3,
    const float* __restrict__ graphs,
    const float* __restrict__ Adj,
    const float* __restrict__ W3,
    const float* __restrict__ b3,
    float* __restrict__ out) {

    __shared__ unsigned short Hs[4][4][NB][8];
    __shared__ uint2 Gbf4[OG * 625];
    __shared__ unsigned short Gbf1[OG * 625];
    __shared__ unsigned short W3kmh[K_ * OG * C_];
    __shared__ float biasS[NB];

    const int tid = threadIdx.x;
    int bid = blockIdx.x;
    bid = (bid & 7) * 128 + (bid >> 3);
    const int obase = (bid & 31) * OG;
    const int n = bid >> 5;
    const int lane = tid & 63;
    const int wv_ = tid >> 6;

    const size_t kstride = (size_t)N_ * O_ * 625;
    for (int i = tid; i < OG * 625; i += 256) {
        int o = i / 625, uv = i - o * 625;
        int u = uv / 25, v = uv - u * 25;
        size_t gb = ((size_t)n * O_ + obase + o) * 625 + uv;
        float g0 = graphs[gb]               + Adj[uv];
        float g1 = graphs[gb + kstride]     + Adj[625 + uv];
        float g2 = graphs[gb + 2 * kstride] + Adj[1250 + uv];
        float g3 = graphs[gb + 3 * kstride] + Adj[1875 + uv];
        float g4 = graphs[gb + 4 * kstride] + Adj[2500 + uv];
        int idx = o * 625 + v * 25 + u;
        uint2 w; w.x = pk2(g0, g1); w.y = pk2(g2, g3);
        Gbf4[idx] = w;
        Gbf1[idx] = f2bf(g4);
    }
    for (int i = tid; i < K_ * OG * C_; i += 256) {
        int k = i / (OG * C_);
        int rem = i - k * (OG * C_);
        int o = rem >> 6, c = rem & 63;
        W3kmh[(k * OG + o) * C_ + c] = f2bf(W3[((size_t)k * O_ + obase + o) * C_ + c]);
    }
    __syncthreads();

    if (tid < NB) {
        int o = tid >> 5, u = tid & 31;
        float bv = 0.f;
        if (u < U_) {
            float s0 = 0.f, s1 = 0.f, s2 = 0.f, s3 = 0.f, s4 = 0.f;
            for (int v = 0; v < V_; ++v) {
                int idx = o * 625 + v * 25 + u;
                uint2 w = Gbf4[idx];
                s0 += bf_lo(w.x); s1 += bf_hi(w.x);
                s2 += bf_lo(w.y); s3 += bf_hi(w.y);
                s4 += bf2f(Gbf1[idx]);
            }
            bv = s0 * b3[0 * O_ + obase + o] + s1 * b3[1 * O_ + obase + o]
               + s2 * b3[2 * O_ + obase + o] + s3 * b3[3 * O_ + obase + o]
               + s4 * b3[4 * O_ + obase + o];
        }
        biasS[tid] = bv;
    }

    const int sl = wv_;
    const int hncol = lane;
    const int ho = hncol >> 5;
    const int hu = hncol & 31;
    const uint2* gp4 = &Gbf4[ho * 625 + hu];
    const unsigned short* gp1 = &Gbf1[ho * 625 + hu];
    const unsigned short* wbh = &W3kmh[ho * C_ + sl * 8];
    char* hwb = (char*)&Hs[0][sl][hncol][0];

    auto h_form = [&](char* hwp, const int parOff, f32x4 g, float g5) {
        float gk[5] = {g[0], g[1], g[2], g[3], g5};
        float h0 = 0.f, h1 = 0.f, h2 = 0.f, h3 = 0.f;
        float h4 = 0.f, h5 = 0.f, h6 = 0.f, h7 = 0.f;
#pragma unroll
        for (int k = 0; k < K_; ++k) {
            uint4 wk = *(const uint4*)(wbh + parOff + k * (OG * C_));
            float gv_ = gk[k];
            h0 += bf_lo(wk.x) * gv_; h1 += bf_hi(wk.x) * gv_;
            h2 += bf_lo(wk.y) * gv_; h3 += bf_hi(wk.y) * gv_;
            h4 += bf_lo(wk.z) * gv_; h5 += bf_hi(wk.z) * gv_;
            h6 += bf_lo(wk.w) * gv_; h7 += bf_hi(wk.w) * gv_;
        }
        uint4 hv;
        hv.x = cvtpk(h0, h1); hv.y = cvtpk(h2, h3);
        hv.z = cvtpk(h4, h5); hv.w = cvtpk(h6, h7);
        *(uint4*)hwp = hv;
    };
    auto ld_g = [&](int voff25, f32x4& g, float& g5) {
        if (hu < U_) {
            uint2 gw = gp4[voff25];
            g[0] = bf_lo(gw.x); g[1] = bf_hi(gw.x);
            g[2] = bf_lo(gw.y); g[3] = bf_hi(gw.y);
            g5 = bf2f(gp1[voff25]);
        } else { g = (f32x4){0.f, 0.f, 0.f, 0.f}; g5 = 0.f; }
    };

    const int wm = wv_;
    const int lr = lane & 15;
    const int eg = lane >> 4;

    f32x4 acc[4][4];
#pragma unroll
    for (int mt = 0; mt < 4; ++mt)
#pragma unroll
        for (int nt = 0; nt < 4; ++nt) acc[mt][nt] = (f32x4){0.f, 0.f, 0.f, 0.f};

    const unsigned short* An = xT3 + (size_t)n * (T_ * CV);
    const unsigned short* a0 = An + ((size_t)((wm * 4 + 0) * 200 + eg)) * 128 + lr * 8;
    const unsigned short* a1 = a0 + 200 * 128;
    const unsigned short* a2 = a0 + 400 * 128;
    const unsigned short* a3 = a0 + 600 * 128;
    const char* hrb = (const char*)&Hs[0][eg][lr][0];

    auto consume = [&](int sub, int bufb) {
        uint4 av0 = *(const uint4*)(a0 + sub);
        uint4 av1 = *(const uint4*)(a1 + sub);
        uint4 av2 = *(const uint4*)(a2 + sub);
        uint4 av3 = *(const uint4*)(a3 + sub);
        bf16x8 b[4];
#pragma unroll
        for (int nt = 0; nt < 4; ++nt)
            b[nt] = *(const bf16x8*)(hrb + bufb + nt * 256);
        __builtin_amdgcn_s_setprio(1);
        union { uint4 u; bf16x8 h; } c0, c1, c2, c3;
        c0.u = av0; c1.u = av1; c2.u = av2; c3.u = av3;
#pragma unroll
        for (int nt = 0; nt < 4; ++nt) acc[0][nt] = __builtin_amdgcn_mfma_f32_16x16x32_bf16(c0.h, b[nt], acc[0][nt], 0, 0, 0);
#pragma unroll
        for (int nt = 0; nt < 4; ++nt) acc[1][nt] = __builtin_amdgcn_mfma_f32_16x16x32_bf16(c1.h, b[nt], acc[1][nt], 0, 0, 0);
#pragma unroll
        for (int nt = 0; nt < 4; ++nt) acc[2][nt] = __builtin_amdgcn_mfma_f32_16x16x32_bf16(c2.h, b[nt], acc[2][nt], 0, 0, 0);
#pragma unroll
        for (int nt = 0; nt < 4; ++nt) acc[3][nt] = __builtin_amdgcn_mfma_f32_16x16x32_bf16(c3.h, b[nt], acc[3][nt], 0, 0, 0);
        __builtin_amdgcn_s_setprio(0);
    };

    f32x4 gv; float gv5;
    ld_g(0, gv, gv5);
    h_form(hwb, 0, gv, gv5);
    h_form(hwb + 4096, 32, gv, gv5);
    __syncthreads();

    for (int kc2 = 0; kc2 < 25; ++kc2) {
        const int rb = (kc2 & 1) * 8192;
        const int wb = 8192 - rb;
        if (kc2 + 1 < 25) ld_g((kc2 + 1) * 25, gv, gv5);
        consume(0, rb);
        consume(512, rb + 4096);
        if (kc2 + 1 < 25) {
            h_form(hwb + wb, 0, gv, gv5);
            h_form(hwb + wb + 4096, 32, gv, gv5);
        }
        __syncthreads();
        a0 += 1024; a1 += 1024; a2 += 1024; a3 += 1024;
    }

#pragma unroll
    for (int nt = 0; nt < 4; ++nt) {
        int ncol = nt * 16 + lr;
        int ol = ncol >> 5;
        int u  = ncol & 31;
        if (u < U_) {
            float bv = biasS[ncol];
            float* ob = out + ((size_t)n * O_ + obase + ol) * T_ * V_ + u;
#pragma unroll
            for (int mt = 0; mt < 4; ++mt) {
                int t0 = wm * 64 + mt * 16 + eg * 4;
#pragma unroll
                for (int r2 = 0; r2 < 4; ++r2)
                    ob[(size_t)(t0 + r2) * V_] = acc[mt][nt][r2] + bv;
            }
        }
    }
}

// ---------------------------------------------------------------------------
// k_main_slow (tier 3, proven R2 path)
// ---------------------------------------------------------------------------
#define OB 4
#define TB 64
__global__ __launch_bounds__(256, 1) void k_main_slow(
    const float* __restrict__ x, const float* __restrict__ graphs,
    const float* __restrict__ A, const float* __restrict__ W3,
    const float* __restrict__ b3, float* __restrict__ out) {
    int bid = blockIdx.x;
    int tb = bid & 3;
    int ob = (bid >> 2) & 15;
    int n  = bid >> 6;
    int tid = threadIdx.x;
    int ol = tid >> 6;
    int tl = tid & 63;
    int t = tb * TB + tl;
    int o = ob * OB + ol;

    __shared__ float Gs[K_][OB][V_][28];
    __shared__ float W3s[K_][OB][C_];
    __shared__ float b3s[K_][OB];

    for (int i = tid; i < K_ * OB * V_ * V_; i += 256) {
        int k   = i / (OB * V_ * V_);
        int rem = i % (OB * V_ * V_);
        int oo  = rem / (V_ * V_);
        int uv  = rem % (V_ * V_);
        Gs[k][oo][uv / V_][uv % V_] =
            graphs[(((size_t)k * N_ + n) * O_ + ob * OB + oo) * (V_ * V_) + uv]
            + A[k * V_ * V_ + uv];
    }
    for (int i = tid; i < K_ * OB * C_; i += 256) {
        int k   = i / (OB * C_);
        int rem = i % (OB * C_);
        int oo  = rem / C_, c = rem % C_;
        W3s[k][oo][c] = W3[((size_t)k * O_ + ob * OB + oo) * C_ + c];
    }
    if (tid < K_ * OB) b3s[tid / OB][tid % OB] = b3[(tid / OB) * O_ + ob * OB + tid % OB];
    __syncthreads();

    float x2[K_][V_];
#pragma unroll
    for (int k = 0; k < K_; ++k)
#pragma unroll
        for (int v = 0; v < V_; ++v) x2[k][v] = b3s[k][ol];

    const float* xb = x + ((size_t)n * C_ * T_ + t) * V_;
    for (int c = 0; c < C_; ++c) {
        const float* p = xb + (size_t)c * T_ * V_;
        float xv[V_];
#pragma unroll
        for (int v = 0; v < V_; ++v) xv[v] = p[v];
#pragma unroll
        for (int k = 0; k < K_; ++k) {
            float w = W3s[k][ol][c];
#pragma unroll
            for (int v = 0; v < V_; ++v) x2[k][v] += w * xv[v];
        }
    }

    float acc[V_];
#pragma unroll
    for (int u = 0; u < V_; ++u) acc[u] = 0.0f;
#pragma unroll
    for (int k = 0; k < K_; ++k) {
#pragma unroll
        for (int u = 0; u < V_; ++u) {
            const float* gr = &Gs[k][ol][u][0];
            float s = 0.0f;
#pragma unroll
            for (int v = 0; v < V_; ++v) s += gr[v] * x2[k][v];
            acc[u] += s;
        }
    }
    float* po = out + (((size_t)n * O_ + o) * T_ + t) * V_;
#pragma unroll
    for (int u = 0; u < V_; ++u) po[u] = acc[u];
}

// ---------------------------------------------------------------------------
extern "C" void kernel_launch(void* const* d_in, const int* in_sizes, int n_in,
                              void* d_out, int out_size, void* d_ws, size_t ws_size,
                              hipStream_t stream) {
    const float* x   = (const float*)d_in[0];
    const float* A   = (const float*)d_in[1];
    const float* W11 = (const float*)d_in[2];
    const float* b11 = (const float*)d_in[3];
    const float* W12 = (const float*)d_in[4];
    const float* b12 = (const float*)d_in[5];
    const float* W2  = (const float*)d_in[6];
    const float* b2  = (const float*)d_in[7];
    const float* W3  = (const float*)d_in[8];
    const float* b3  = (const float*)d_in[9];
    const float* W4  = (const float*)d_in[10];
    const float* b4  = (const float*)d_in[11];

    float* out    = (float*)d_out;
    float* graphs = out + OUT_ELEMS;   // second tuple element

    const size_t xT_bytes = sizeof(unsigned short) * (size_t)N_ * T_ * CV;  // 26.2 MB
    const size_t pp_bytes = sizeof(float) * (size_t)N_ * 16 * CV;           //  3.3 MB
    const size_t gf_bytes = sizeof(unsigned short) * (size_t)N_ * 64 * 32 * 128; // 16.8 MB
    const size_t hdr      = (size_t)(1 << 20);
    const bool tier1 = (ws_size >= hdr + xT_bytes + pp_bytes + gf_bytes);
    const bool tier2 = (ws_size >= hdr + xT_bytes + pp_bytes);

    const size_t poolElems = (size_t)N_ * C_ * V_;
    const size_t tElems    = (size_t)K_ * N_ * R_ * V_;
    const size_t slowNeed  = (poolElems + 2 * tElems) * sizeof(float);

    float* scratch = (tier2 || ws_size >= slowNeed) ? (float*)d_ws : out;
    float* pool = scratch;
    float* t2v  = scratch + poolElems;
    float* tSv  = t2v + tElems;
    unsigned short* xT3 = (unsigned short*)((char*)d_ws + hdr);
    float* pp = (float*)((char*)d_ws + hdr + xT_bytes);
    unsigned short* gfrag = (unsigned short*)((char*)d_ws + hdr + xT_bytes + pp_bytes);

    if (tier1) {
        k_xcast<<<N_ * 16, 256, 0, stream>>>(x, xT3, pp);
        k_graphs2f<<<K_ * N_ * 2, 512, 0, stream>>>(pp, W11, b11, W12, b12, W2, b2, W4, b4, A, graphs, gfrag);
        k_biasf<<<N_ * 8, 256, 0, stream>>>(graphs, A, b3, gfrag);
        k_main_fac<<<N_ * 4 * 32, 256, 0, stream>>>(xT3, gfrag, W3, out);
    } else if (tier2) {
        k_xcast<<<N_ * 16, 256, 0, stream>>>(x, xT3, pp);
        k_graphs2f<<<K_ * N_ * 2, 512, 0, stream>>>(pp, W11, b11, W12, b12, W2, b2, W4, b4, A, graphs, (unsigned short*)nullptr);
        k_main_fast2<<<N_ * 32, 256, 0, stream>>>(xT3, graphs, A, W3, b3, out);
    } else {
        k_pool  <<<N_ * C_, 256, 0, stream>>>(x, pool);
        k_tvals <<<K_ * N_, 256, 0, stream>>>(pool, W11, b11, W12, b12, W2, b2, t2v, tSv);
        k_graphs<<<K_ * N_, 256, 0, stream>>>(t2v, tSv, W4, b4, graphs);
        k_main_slow<<<N_ * (O_ / OB) * 4, 256, 0, stream>>>(x, graphs, A, W3, b3, out);
    }
}

// Round 20
// 116.760 us; speedup vs baseline: 1.4099x; 1.0767x over previous
//
#include <hip/hip_runtime.h>
#include <cstdint>
#include <cstddef>

#define N_  32
#define C_  64
#define T_  256
#define V_  25
#define R_  8
#define O_  64
#define K_  5
#define NU_ 17
#define U_  25
#define CV  (C_ * V_)        // 1600
#define OG  2                // o's per block (tier-1 and tier-2 k_main)
#define NB  (OG * 32)        // 64 ncols (tier-2)

#define OUT_ELEMS ((size_t)N_ * O_ * T_ * V_)   // 13,107,200

typedef __attribute__((ext_vector_type(8))) short bf16x8;
typedef __attribute__((ext_vector_type(4))) float f32x4;

static __device__ __forceinline__ unsigned short f2bf(float f) {
    union { float f; unsigned u; } c; c.f = f;
    return (unsigned short)((c.u + 0x8000u) >> 16);
}
static __device__ __forceinline__ float bf2f(unsigned short h) {
    union { unsigned u; float f; } c; c.u = ((unsigned)h) << 16; return c.f;
}
static __device__ __forceinline__ float bf_lo(unsigned d) {
    union { unsigned u; float f; } c; c.u = d << 16; return c.f;
}
static __device__ __forceinline__ float bf_hi(unsigned d) {
    union { unsigned u; float f; } c; c.u = d & 0xFFFF0000u; return c.f;
}
static __device__ __forceinline__ unsigned pk2(float a, float b) {
    union { float f; unsigned u; } ca, cb; ca.f = a; cb.f = b;
    return ((ca.u + 0x8000u) >> 16) | ((cb.u + 0x8000u) & 0xFFFF0000u);
}
static __device__ __forceinline__ unsigned cvtpk(float a, float b) {
    unsigned r;
    asm("v_cvt_pk_bf16_f32 %0, %1, %2" : "=v"(r) : "v"(a), "v"(b));
    return r;
}
static __device__ __forceinline__ bf16x8 asbf(uint4 u) {
    union { uint4 u; bf16x8 h; } c; c.u = u; return c.h;
}
// x2h swizzle class in USHORT units (16B slot = 8 ushorts): bits 3-5.
static __device__ __forceinline__ int clsw(int t) {
    return ((t ^ (t >> 3)) & 7) << 3;
}

// ---------------------------------------------------------------------------
// k_xcast: fragment-native xT3 with cv' = v*64+c ordering:
//   xT3[n][tt(16)][s'(200)][tl(16)][ke(8)],  s' = v*8 + c/8, ke = c&7.
// ---------------------------------------------------------------------------
__global__ void k_xcast(const float* __restrict__ x, unsigned short* __restrict__ xT3,
                        float* __restrict__ pp) {
    __shared__ unsigned short tile[C_][408];   // [c][t*25+v], row 816 B
    int bid = blockIdx.x;
    int n = bid >> 4, tb = bid & 15;
    int tid = threadIdx.x;
    const float* xb = x + (size_t)n * C_ * T_ * V_ + tb * 400;
#pragma unroll
    for (int it = 0; it < 25; ++it) {
        int i = it * 256 + tid;          // < 6400
        int c = i / 100, q = i - c * 100;
        float4 v4 = *(const float4*)(xb + (size_t)c * (T_ * V_) + q * 4);
        uint2 w;
        w.x = pk2(v4.x, v4.y);
        w.y = pk2(v4.z, v4.w);
        *(uint2*)&tile[c][q * 4] = w;
    }
    __syncthreads();
    unsigned short* dstb = xT3 + ((size_t)(n * 16 + tb) * 200) * 128;
    for (int i = tid; i < 200 * 16; i += 256) {
        int sp = i >> 4, tl = i & 15;
        int v = sp >> 3, c0 = (sp & 7) * 8;
        unsigned short h[8];
#pragma unroll
        for (int j = 0; j < 8; ++j) h[j] = tile[c0 + j][tl * 25 + v];
        uint4 pk;
        pk.x = (unsigned)h[0] | ((unsigned)h[1] << 16);
        pk.y = (unsigned)h[2] | ((unsigned)h[3] << 16);
        pk.z = (unsigned)h[4] | ((unsigned)h[5] << 16);
        pk.w = (unsigned)h[6] | ((unsigned)h[7] << 16);
        *(uint4*)(dstb + (size_t)sp * 128 + tl * 8) = pk;
    }
    float* ppd = pp + ((size_t)n * 16 + tb) * CV;
    for (int e = tid; e < CV; e += 256) {
        int c = e / 25, v = e - c * 25;
        float s = 0.f;
#pragma unroll
        for (int t = 0; t < 16; ++t) s += bf2f(tile[c][t * 25 + v]);
        ppd[e] = s;
    }
}

// classic pool (slow tier)
__global__ void k_pool(const float* __restrict__ x, float* __restrict__ pool) {
    int nc = blockIdx.x;
    int t  = threadIdx.x;
    const float* px = x + ((size_t)nc * T_ + t) * V_;
    float acc[V_];
#pragma unroll
    for (int v = 0; v < V_; ++v) acc[v] = px[v];
#pragma unroll
    for (int off = 32; off > 0; off >>= 1) {
#pragma unroll
        for (int v = 0; v < V_; ++v) acc[v] += __shfl_down(acc[v], off, 64);
    }
    __shared__ float sm[4][V_];
    int wave = t >> 6, lane = t & 63;
    if (lane == 0) {
#pragma unroll
        for (int v = 0; v < V_; ++v) sm[wave][v] = acc[v];
    }
    __syncthreads();
    if (t < V_) {
        float s = sm[0][t] + sm[1][t] + sm[2][t] + sm[3][t];
        pool[(size_t)nc * V_ + t] = s * (1.0f / T_);
    }
}

// ---------------------------------------------------------------------------
// k_tvals (slow tier only)
// ---------------------------------------------------------------------------
__global__ void k_tvals(const float* __restrict__ pool,
                        const float* __restrict__ W11, const float* __restrict__ b11,
                        const float* __restrict__ W12, const float* __restrict__ b12,
                        const float* __restrict__ W2,  const float* __restrict__ b2,
                        float* __restrict__ t2o, float* __restrict__ tSo) {
    int kn = blockIdx.x;
    int k = kn / N_, n = kn % N_;
    int tid = threadIdx.x;
    int r = tid >> 5, v = tid & 31;
    if (v >= V_) return;
    const float* pp = pool + (size_t)n * C_ * V_ + v;
    const float* w2 = W2 + ((size_t)k * R_ + r) * C_;
    const float* w1 = ((v < NU_) ? W11 : W12) + ((size_t)k * R_ + r) * C_;
    float a2 = b2[k * R_ + r];
    float a1 = (v < NU_) ? b11[k * R_ + r] : b12[k * R_ + r];
    for (int c = 0; c < C_; ++c) {
        float p = pp[(size_t)c * V_];
        a2 += w2[c] * p;
        a1 += w1[c] * p;
    }
    size_t idx = (((size_t)k * N_ + n) * R_ + r) * V_ + v;
    t2o[idx] = a2;
    tSo[idx] = a1;
}

// ---------------------------------------------------------------------------
// k_graphs (slow tier)
// ---------------------------------------------------------------------------
__global__ void k_graphs(const float* __restrict__ t2v, const float* __restrict__ tSv,
                         const float* __restrict__ W4, const float* __restrict__ b4,
                         float* __restrict__ graphs) {
    int kn = blockIdx.x;
    int k = kn / N_, n = kn % N_;
    int kup = (k + 1) % K_;
    __shared__ float F[R_][V_ * V_];
    __shared__ float w4s[O_][R_];
    __shared__ float b4s[O_];
    int tid = threadIdx.x;
    for (int i = tid; i < O_ * R_; i += 256) w4s[i / R_][i % R_] = W4[(size_t)k * O_ * R_ + i];
    if (tid < O_) b4s[tid] = b4[k * O_ + tid];
    for (int idx = tid; idx < R_ * V_ * V_; idx += 256) {
        int r = idx / (V_ * V_), uv = idx % (V_ * V_);
        int u = uv / V_, v = uv % V_;
        int ks = (u < NU_) ? kup : k;
        size_t base = (((size_t)ks * N_ + n) * R_ + r) * V_;
        F[r][uv] = tanhf(tSv[base + u] - t2v[base + v]);
    }
    __syncthreads();
    float* gout = graphs + ((size_t)k * N_ + n) * O_ * (V_ * V_);
    for (int idx = tid; idx < O_ * V_ * V_; idx += 256) {
        int o = idx / (V_ * V_), uv = idx % (V_ * V_);
        float a = b4s[o];
#pragma unroll
        for (int r = 0; r < R_; ++r) a += w4s[o][r] * F[r][uv];
        gout[idx] = a;
    }
}

// ---------------------------------------------------------------------------
// k_graphs2f: fused pool + tvals + F + graphs; ALSO emits Gfrag (tier 1):
//   gfrag[n][o(64)][u(32)][kv(128)] bf16 = graphs + Adj.
// ---------------------------------------------------------------------------
__global__ void k_graphs2f(const float* __restrict__ pp,
                           const float* __restrict__ W11, const float* __restrict__ b11,
                           const float* __restrict__ W12, const float* __restrict__ b12,
                           const float* __restrict__ W2,  const float* __restrict__ b2,
                           const float* __restrict__ W4,  const float* __restrict__ b4,
                           const float* __restrict__ Adj,
                           float* __restrict__ graphs,
                           unsigned short* __restrict__ gfrag) {
    int bid = blockIdx.x;
    int og = bid & 1;
    int kn = bid >> 1;
    int k = kn / N_, n = kn % N_;
    int kup = (k + 1) % K_;
    __shared__ float poolL[CV];
    __shared__ float t2s[2][R_][V_];
    __shared__ float tSs[2][R_][V_];
    __shared__ float F[R_][V_ * V_];
    __shared__ float w4s[O_][R_];
    __shared__ float b4s[O_];
    int tid = threadIdx.x;
    for (int i = tid; i < O_ * R_; i += 512) w4s[i / R_][i % R_] = W4[(size_t)k * O_ * R_ + i];
    if (tid < O_) b4s[tid] = b4[k * O_ + tid];
    const float* ppn = pp + (size_t)n * 16 * CV;
    for (int i = tid; i < CV; i += 512) {
        float s = 0.f;
#pragma unroll
        for (int tb = 0; tb < 16; ++tb) s += ppn[(size_t)tb * CV + i];
        poolL[i] = s * (1.0f / T_);
    }
    __syncthreads();
    for (int i = tid; i < 2 * R_ * V_; i += 512) {
        int ks = i / (R_ * V_);
        int rem = i - ks * (R_ * V_);
        int r = rem / V_, v = rem - r * V_;
        int kk = ks ? kup : k;
        const float* w2 = W2 + ((size_t)kk * R_ + r) * C_;
        const float* w1 = ((v < NU_) ? W11 : W12) + ((size_t)kk * R_ + r) * C_;
        float a2 = b2[kk * R_ + r];
        float a1 = (v < NU_) ? b11[kk * R_ + r] : b12[kk * R_ + r];
        for (int c = 0; c < C_; ++c) {
            float p = poolL[c * 25 + v];
            a2 += w2[c] * p;
            a1 += w1[c] * p;
        }
        t2s[ks][r][v] = a2;
        tSs[ks][r][v] = a1;
    }
    __syncthreads();
    for (int idx = tid; idx < R_ * V_ * V_; idx += 512) {
        int r = idx / (V_ * V_), uv = idx % (V_ * V_);
        int u = uv / V_, v = uv % V_;
        int ks = (u < NU_) ? 1 : 0;
        F[r][uv] = tanhf(tSs[ks][r][u] - t2s[ks][r][v]);
    }
    __syncthreads();
    float* gout = graphs + ((size_t)k * N_ + n) * O_ * (V_ * V_);
    const int half = O_ * V_ * V_ / 2;
    for (int idx = og * half + tid; idx < (og + 1) * half; idx += 512) {
        int o = idx / (V_ * V_), uv = idx % (V_ * V_);
        float a = b4s[o];
#pragma unroll
        for (int r = 0; r < R_; ++r) a += w4s[o][r] * F[r][uv];
        gout[idx] = a;
        if (gfrag) {
            int u = uv / 25, v = uv - u * 25;
            gfrag[(((size_t)n * 64 + o) * 32 + u) * 128 + k * 25 + v] =
                f2bf(a + Adj[k * 625 + uv]);
        }
    }
}

// ---------------------------------------------------------------------------
// k_biasf: gfrag[n][o][u][125] = sum_k b3[k,o] * sum_v (graphs+Adj)
// ---------------------------------------------------------------------------
__global__ void k_biasf(const float* __restrict__ graphs, const float* __restrict__ Adj,
                        const float* __restrict__ b3, unsigned short* __restrict__ gfrag) {
    int bid = blockIdx.x;               // n*8 + og8
    int n = bid >> 3, og8 = bid & 7;
    int ol = threadIdx.x >> 5, u = threadIdx.x & 31;
    int o = og8 * 8 + ol;
    if (u >= U_) return;
    float s = 0.f;
    for (int k = 0; k < K_; ++k) {
        const float* gp = graphs + (((size_t)k * N_ + n) * O_ + o) * 625 + u * 25;
        const float* ap = Adj + k * 625 + u * 25;
        float t = 0.f;
#pragma unroll
        for (int v = 0; v < V_; ++v) t += gp[v] + ap[v];
        s += t * b3[k * O_ + o];
    }
    gfrag[(((size_t)n * 64 + o) * 32 + u) * 128 + 125] = f2bf(s);
}

// ---------------------------------------------------------------------------
// k_main_fac (tier 1, FACTORED, WAVE-LOCAL, ZERO BARRIERS, MANUAL ILP):
//  R19 structure + explicit latency hiding:
//   - ALL 16 gfrag B-fragment loads issued BEFORE stage A (64 VGPR held);
//     their latency hides under stage A, stage B starts operand-resident.
//   - stage A uses an explicit 2-deep prefetch ring (qa/qb[v&1], fully
//     unrolled -> static) so loads for v+2 fly while v computes.
//  4 blocks/CU (32 KB LDS), VGPR budget 128. WRITE_SIZE = spill watchdog.
// ---------------------------------------------------------------------------
__global__ __launch_bounds__(256, 4) void k_main_fac(
    const unsigned short* __restrict__ xT3,   // [N][16][200][16][8] bf16 bits
    const unsigned short* __restrict__ gfrag, // [N][64][32][128] bf16
    const float* __restrict__ W3,             // [K][O][C]
    float* __restrict__ out) {

    __shared__ unsigned short x2h[2 * 64 * 128];   // 32 KB

    const int tid = threadIdx.x;
    int raw = blockIdx.x;
    int bid = (raw & 7) * 512 + (raw >> 3);   // XCD swizzle (4096 % 8 == 0)
    const int og = bid & 31;
    const int tb = (bid >> 5) & 3;
    const int n  = bid >> 7;
    const int obase = og * 2;
    const int tgb = tb * 64;
    const int lane = tid & 63;
    const int w = tid >> 6;        // wave = t-tile
    const int lr = lane & 15;
    const int eg = lane >> 4;

    // ---- pre-issue ALL 16 gfrag B-frag loads (independent of stage A) ----
    uint4 bfr[2][2][4];
    {
        const unsigned short* gb = gfrag + (((size_t)n * 64 + obase) * 32) * 128;
#pragma unroll
        for (int o = 0; o < 2; ++o)
#pragma unroll
            for (int nt = 0; nt < 2; ++nt)
#pragma unroll
                for (int ks = 0; ks < 4; ++ks)
                    bfr[o][nt][ks] = *(const uint4*)(gb + (size_t)o * 4096
                                                     + (nt * 16 + lr) * 128 + ks * 32 + eg * 8);
    }

    // ---- W3 B-frags in registers (col = lr -> ncol = k*2+o, elems = c) ----
    bf16x8 wb0, wb1;
    {
        short h0[8] = {0,0,0,0,0,0,0,0}, h1[8] = {0,0,0,0,0,0,0,0};
        if (lr < 10) {
            int k = lr >> 1, o = lr & 1;
            const float* wp = W3 + ((size_t)k * O_ + obase + o) * C_;
#pragma unroll
            for (int e = 0; e < 8; ++e) {
                h0[e] = (short)f2bf(wp[eg * 8 + e]);
                h1[e] = (short)f2bf(wp[32 + eg * 8 + e]);
            }
        }
        wb0 = (bf16x8){h0[0], h0[1], h0[2], h0[3], h0[4], h0[5], h0[6], h0[7]};
        wb1 = (bf16x8){h1[0], h1[1], h1[2], h1[3], h1[4], h1[5], h1[6], h1[7]};
    }

    // ---- per-wave pad init: lanes 0..31 cover (o, 16 wave-local t's) ----
    if (lane < 32) {
        int o = lane >> 4, t = w * 16 + (lane & 15);
        int cls = clsw(t);
        int rowb = o * 8192 + t * 128;
        x2h[rowb + (125 ^ cls)] = 0x3F80;   // 1.0 in bf16 (bias column)
        x2h[rowb + (126 ^ cls)] = 0;
        x2h[rowb + (127 ^ cls)] = 0;
    }

    // ---- stage A: 25 per-v GEMMs, explicit 2-deep prefetch ring ----
    {
        const int ttb = tb * 4 + w;
        const unsigned short* pA = xT3 + (size_t)n * (T_ * CV)
                                 + ((size_t)(ttb * 200) + eg) * 128 + lr * 8;
        const int kA = lr >> 1, oA = lr & 1;
        const int tl0 = w * 16 + eg * 4;
        uint4 qa[2], qb[2];
        qa[0] = *(const uint4*)(pA);          qb[0] = *(const uint4*)(pA + 512);
        qa[1] = *(const uint4*)(pA + 1024);   qb[1] = *(const uint4*)(pA + 1536);
#pragma unroll
        for (int v = 0; v < 25; ++v) {
            uint4 a0 = qa[v & 1], a1 = qb[v & 1];
            if (v + 2 < 25) {
                qa[v & 1] = *(const uint4*)(pA + (v + 2) * 1024);
                qb[v & 1] = *(const uint4*)(pA + (v + 2) * 1024 + 512);
            }
            f32x4 d = {0.f, 0.f, 0.f, 0.f};
            d = __builtin_amdgcn_mfma_f32_16x16x32_bf16(asbf(a0), wb0, d, 0, 0, 0);
            d = __builtin_amdgcn_mfma_f32_16x16x32_bf16(asbf(a1), wb1, d, 0, 0, 0);
            if (lr < 10) {
                int kv = kA * 25 + v;
#pragma unroll
                for (int r2 = 0; r2 < 4; ++r2) {
                    int t = tl0 + r2;
                    x2h[oA * 8192 + t * 128 + (kv ^ clsw(t))] = f2bf(d[r2]);
                }
            }
        }
    }
    // NO barrier: stage-B reads are wave-local (same-wave lgkmcnt ordering).

    // ---- stage B: per wave M=16(t) x N=64(2o x 2nt), K=128 ----
    f32x4 acc[2][2];
#pragma unroll
    for (int o = 0; o < 2; ++o)
#pragma unroll
        for (int nt = 0; nt < 2; ++nt) acc[o][nt] = (f32x4){0.f, 0.f, 0.f, 0.f};

    const int tB = w * 16 + lr;
    const int clsB = clsw(tB);
    const int rowB = tB * 128;
#pragma unroll
    for (int o = 0; o < 2; ++o) {
#pragma unroll
        for (int ks = 0; ks < 4; ++ks) {
            const int kv0 = ks * 32 + eg * 8;
            bf16x8 af = *(const bf16x8*)&x2h[o * 8192 + rowB + (kv0 ^ clsB)];
            acc[o][0] = __builtin_amdgcn_mfma_f32_16x16x32_bf16(af, asbf(bfr[o][0][ks]), acc[o][0], 0, 0, 0);
            acc[o][1] = __builtin_amdgcn_mfma_f32_16x16x32_bf16(af, asbf(bfr[o][1][ks]), acc[o][1], 0, 0, 0);
        }
    }

    // ---- epilogue: C/D col = lr (u), rows = eg*4+r2 (t-in-tile) ----
#pragma unroll
    for (int o = 0; o < 2; ++o) {
        float* ob = out + ((size_t)n * O_ + obase + o) * T_ * V_;
#pragma unroll
        for (int nt = 0; nt < 2; ++nt) {
            int u = nt * 16 + lr;
            if (u < U_) {
#pragma unroll
                for (int r2 = 0; r2 < 4; ++r2) {
                    int t = tgb + w * 16 + eg * 4 + r2;
                    ob[(size_t)t * V_ + u] = acc[o][nt][r2];
                }
            }
        }
    }
}

// ---------------------------------------------------------------------------
// k_main_fast2 (tier 2 = proven R16 kernel)
// ---------------------------------------------------------------------------
__global__ __launch_bounds__(256, 4) void k_main_fast2(
    const unsigned short* __restrict__ xT3,
    const float* __restrict__ graphs,
    const float* __restrict__ Adj,
    const float* __restrict__ W3,
    const float* __restrict__ b3,
    float* __restrict__ out) {

    __shared__ unsigned short Hs[4][4][NB][8];
    __shared__ uint2 Gbf4[OG * 625];
    __shared__ unsigned short Gbf1[OG * 625];
    __shared__ unsigned short W3kmh[K_ * OG * C_];
    __shared__ float biasS[NB];

    const int tid = threadIdx.x;
    int bid = blockIdx.x;
    bid = (bid & 7) * 128 + (bid >> 3);
    const int obase = (bid & 31) * OG;
    const int n = bid >> 5;
    const int lane = tid & 63;
    const int wv_ = tid >> 6;

    const size_t kstride = (size_t)N_ * O_ * 625;
    for (int i = tid; i < OG * 625; i += 256) {
        int o = i / 625, uv = i - o * 625;
        int u = uv / 25, v = uv - u * 25;
        size_t gb = ((size_t)n * O_ + obase + o) * 625 + uv;
        float g0 = graphs[gb]               + Adj[uv];
        float g1 = graphs[gb + kstride]     + Adj[625 + uv];
        float g2 = graphs[gb + 2 * kstride] + Adj[1250 + uv];
        float g3 = graphs[gb + 3 * kstride] + Adj[1875 + uv];
        float g4 = graphs[gb + 4 * kstride] + Adj[2500 + uv];
        int idx = o * 625 + v * 25 + u;
        uint2 w; w.x = pk2(g0, g1); w.y = pk2(g2, g3);
        Gbf4[idx] = w;
        Gbf1[idx] = f2bf(g4);
    }
    for (int i = tid; i < K_ * OG * C_; i += 256) {
        int k = i / (OG * C_);
        int rem = i - k * (OG * C_);
        int o = rem >> 6, c = rem & 63;
        W3kmh[(k * OG + o) * C_ + c] = f2bf(W3[((size_t)k * O_ + obase + o) * C_ + c]);
    }
    __syncthreads();

    if (tid < NB) {
        int o = tid >> 5, u = tid & 31;
        float bv = 0.f;
        if (u < U_) {
            float s0 = 0.f, s1 = 0.f, s2 = 0.f, s3 = 0.f, s4 = 0.f;
            for (int v = 0; v < V_; ++v) {
                int idx = o * 625 + v * 25 + u;
                uint2 w = Gbf4[idx];
                s0 += bf_lo(w.x); s1 += bf_hi(w.x);
                s2 += bf_lo(w.y); s3 += bf_hi(w.y);
                s4 += bf2f(Gbf1[idx]);
            }
            bv = s0 * b3[0 * O_ + obase + o] + s1 * b3[1 * O_ + obase + o]
               + s2 * b3[2 * O_ + obase + o] + s3 * b3[3 * O_ + obase + o]
               + s4 * b3[4 * O_ + obase + o];
        }
        biasS[tid] = bv;
    }

    const int sl = wv_;
    const int hncol = lane;
    const int ho = hncol >> 5;
    const int hu = hncol & 31;
    const uint2* gp4 = &Gbf4[ho * 625 + hu];
    const unsigned short* gp1 = &Gbf1[ho * 625 + hu];
    const unsigned short* wbh = &W3kmh[ho * C_ + sl * 8];
    char* hwb = (char*)&Hs[0][sl][hncol][0];

    auto h_form = [&](char* hwp, const int parOff, f32x4 g, float g5) {
        float gk[5] = {g[0], g[1], g[2], g[3], g5};
        float h0 = 0.f, h1 = 0.f, h2 = 0.f, h3 = 0.f;
        float h4 = 0.f, h5 = 0.f, h6 = 0.f, h7 = 0.f;
#pragma unroll
        for (int k = 0; k < K_; ++k) {
            uint4 wk = *(const uint4*)(wbh + parOff + k * (OG * C_));
            float gv_ = gk[k];
            h0 += bf_lo(wk.x) * gv_; h1 += bf_hi(wk.x) * gv_;
            h2 += bf_lo(wk.y) * gv_; h3 += bf_hi(wk.y) * gv_;
            h4 += bf_lo(wk.z) * gv_; h5 += bf_hi(wk.z) * gv_;
            h6 += bf_lo(wk.w) * gv_; h7 += bf_hi(wk.w) * gv_;
        }
        uint4 hv;
        hv.x = cvtpk(h0, h1); hv.y = cvtpk(h2, h3);
        hv.z = cvtpk(h4, h5); hv.w = cvtpk(h6, h7);
        *(uint4*)hwp = hv;
    };
    auto ld_g = [&](int voff25, f32x4& g, float& g5) {
        if (hu < U_) {
            uint2 gw = gp4[voff25];
            g[0] = bf_lo(gw.x); g[1] = bf_hi(gw.x);
            g[2] = bf_lo(gw.y); g[3] = bf_hi(gw.y);
            g5 = bf2f(gp1[voff25]);
        } else { g = (f32x4){0.f, 0.f, 0.f, 0.f}; g5 = 0.f; }
    };

    const int wm = wv_;
    const int lr = lane & 15;
    const int eg = lane >> 4;

    f32x4 acc[4][4];
#pragma unroll
    for (int mt = 0; mt < 4; ++mt)
#pragma unroll
        for (int nt = 0; nt < 4; ++nt) acc[mt][nt] = (f32x4){0.f, 0.f, 0.f, 0.f};

    const unsigned short* An = xT3 + (size_t)n * (T_ * CV);
    const unsigned short* a0 = An + ((size_t)((wm * 4 + 0) * 200 + eg)) * 128 + lr * 8;
    const unsigned short* a1 = a0 + 200 * 128;
    const unsigned short* a2 = a0 + 400 * 128;
    const unsigned short* a3 = a0 + 600 * 128;
    const char* hrb = (const char*)&Hs[0][eg][lr][0];

    auto consume = [&](int sub, int bufb) {
        uint4 av0 = *(const uint4*)(a0 + sub);
        uint4 av1 = *(const uint4*)(a1 + sub);
        uint4 av2 = *(const uint4*)(a2 + sub);
        uint4 av3 = *(const uint4*)(a3 + sub);
        bf16x8 b[4];
#pragma unroll
        for (int nt = 0; nt < 4; ++nt)
            b[nt] = *(const bf16x8*)(hrb + bufb + nt * 256);
        __builtin_amdgcn_s_setprio(1);
        union { uint4 u; bf16x8 h; } c0, c1, c2, c3;
        c0.u = av0; c1.u = av1; c2.u = av2; c3.u = av3;
#pragma unroll
        for (int nt = 0; nt < 4; ++nt) acc[0][nt] = __builtin_amdgcn_mfma_f32_16x16x32_bf16(c0.h, b[nt], acc[0][nt], 0, 0, 0);
#pragma unroll
        for (int nt = 0; nt < 4; ++nt) acc[1][nt] = __builtin_amdgcn_mfma_f32_16x16x32_bf16(c1.h, b[nt], acc[1][nt], 0, 0, 0);
#pragma unroll
        for (int nt = 0; nt < 4; ++nt) acc[2][nt] = __builtin_amdgcn_mfma_f32_16x16x32_bf16(c2.h, b[nt], acc[2][nt], 0, 0, 0);
#pragma unroll
        for (int nt = 0; nt < 4; ++nt) acc[3][nt] = __builtin_amdgcn_mfma_f32_16x16x32_bf16(c3.h, b[nt], acc[3][nt], 0, 0, 0);
        __builtin_amdgcn_s_setprio(0);
    };

    f32x4 gv; float gv5;
    ld_g(0, gv, gv5);
    h_form(hwb, 0, gv, gv5);
    h_form(hwb + 4096, 32, gv, gv5);
    __syncthreads();

    for (int kc2 = 0; kc2 < 25; ++kc2) {
        const int rb = (kc2 & 1) * 8192;
        const int wb = 8192 - rb;
        if (kc2 + 1 < 25) ld_g((kc2 + 1) * 25, gv, gv5);
        consume(0, rb);
        consume(512, rb + 4096);
        if (kc2 + 1 < 25) {
            h_form(hwb + wb, 0, gv, gv5);
            h_form(hwb + wb + 4096, 32, gv, gv5);
        }
        __syncthreads();
        a0 += 1024; a1 += 1024; a2 += 1024; a3 += 1024;
    }

#pragma unroll
    for (int nt = 0; nt < 4; ++nt) {
        int ncol = nt * 16 + lr;
        int ol = ncol >> 5;
        int u  = ncol & 31;
        if (u < U_) {
            float bv = biasS[ncol];
            float* ob = out + ((size_t)n * O_ + obase + ol) * T_ * V_ + u;
#pragma unroll
            for (int mt = 0; mt < 4; ++mt) {
                int t0 = wm * 64 + mt * 16 + eg * 4;
#pragma unroll
                for (int r2 = 0; r2 < 4; ++r2)
                    ob[(size_t)(t0 + r2) * V_] = acc[mt][nt][r2] + bv;
            }
        }
    }
}

// ---------------------------------------------------------------------------
// k_main_slow (tier 3, proven R2 path)
// ---------------------------------------------------------------------------
#define OB 4
#define TB 64
__global__ __launch_bounds__(256, 1) void k_main_slow(
    const float* __restrict__ x, const float* __restrict__ graphs,
    const float* __restrict__ A, const float* __restrict__ W3,
    const float* __restrict__ b3, float* __restrict__ out) {
    int bid = blockIdx.x;
    int tb = bid & 3;
    int ob = (bid >> 2) & 15;
    int n  = bid >> 6;
    int tid = threadIdx.x;
    int ol = tid >> 6;
    int tl = tid & 63;
    int t = tb * TB + tl;
    int o = ob * OB + ol;

    __shared__ float Gs[K_][OB][V_][28];
    __shared__ float W3s[K_][OB][C_];
    __shared__ float b3s[K_][OB];

    for (int i = tid; i < K_ * OB * V_ * V_; i += 256) {
        int k   = i / (OB * V_ * V_);
        int rem = i % (OB * V_ * V_);
        int oo  = rem / (V_ * V_);
        int uv  = rem % (V_ * V_);
        Gs[k][oo][uv / V_][uv % V_] =
            graphs[(((size_t)k * N_ + n) * O_ + ob * OB + oo) * (V_ * V_) + uv]
            + A[k * V_ * V_ + uv];
    }
    for (int i = tid; i < K_ * OB * C_; i += 256) {
        int k   = i / (OB * C_);
        int rem = i % (OB * C_);
        int oo  = rem / C_, c = rem % C_;
        W3s[k][oo][c] = W3[((size_t)k * O_ + ob * OB + oo) * C_ + c];
    }
    if (tid < K_ * OB) b3s[tid / OB][tid % OB] = b3[(tid / OB) * O_ + ob * OB + tid % OB];
    __syncthreads();

    float x2[K_][V_];
#pragma unroll
    for (int k = 0; k < K_; ++k)
#pragma unroll
        for (int v = 0; v < V_; ++v) x2[k][v] = b3s[k][ol];

    const float* xb = x + ((size_t)n * C_ * T_ + t) * V_;
    for (int c = 0; c < C_; ++c) {
        const float* p = xb + (size_t)c * T_ * V_;
        float xv[V_];
#pragma unroll
        for (int v = 0; v < V_; ++v) xv[v] = p[v];
#pragma unroll
        for (int k = 0; k < K_; ++k) {
            float w = W3s[k][ol][c];
#pragma unroll
            for (int v = 0; v < V_; ++v) x2[k][v] += w * xv[v];
        }
    }

    float acc[V_];
#pragma unroll
    for (int u = 0; u < V_; ++u) acc[u] = 0.0f;
#pragma unroll
    for (int k = 0; k < K_; ++k) {
#pragma unroll
        for (int u = 0; u < V_; ++u) {
            const float* gr = &Gs[k][ol][u][0];
            float s = 0.0f;
#pragma unroll
            for (int v = 0; v < V_; ++v) s += gr[v] * x2[k][v];
            acc[u] += s;
        }
    }
    float* po = out + (((size_t)n * O_ + o) * T_ + t) * V_;
#pragma unroll
    for (int u = 0; u < V_; ++u) po[u] = acc[u];
}

// ---------------------------------------------------------------------------
extern "C" void kernel_launch(void* const* d_in, const int* in_sizes, int n_in,
                              void* d_out, int out_size, void* d_ws, size_t ws_size,
                              hipStream_t stream) {
    const float* x   = (const float*)d_in[0];
    const float* A   = (const float*)d_in[1];
    const float* W11 = (const float*)d_in[2];
    const float* b11 = (const float*)d_in[3];
    const float* W12 = (const float*)d_in[4];
    const float* b12 = (const float*)d_in[5];
    const float* W2  = (const float*)d_in[6];
    const float* b2  = (const float*)d_in[7];
    const float* W3  = (const float*)d_in[8];
    const float* b3  = (const float*)d_in[9];
    const float* W4  = (const float*)d_in[10];
    const float* b4  = (const float*)d_in[11];

    float* out    = (float*)d_out;
    float* graphs = out + OUT_ELEMS;   // second tuple element

    const size_t xT_bytes = sizeof(unsigned short) * (size_t)N_ * T_ * CV;  // 26.2 MB
    const size_t pp_bytes = sizeof(float) * (size_t)N_ * 16 * CV;           //  3.3 MB
    const size_t gf_bytes = sizeof(unsigned short) * (size_t)N_ * 64 * 32 * 128; // 16.8 MB
    const size_t hdr      = (size_t)(1 << 20);
    const bool tier1 = (ws_size >= hdr + xT_bytes + pp_bytes + gf_bytes);
    const bool tier2 = (ws_size >= hdr + xT_bytes + pp_bytes);

    const size_t poolElems = (size_t)N_ * C_ * V_;
    const size_t tElems    = (size_t)K_ * N_ * R_ * V_;
    const size_t slowNeed  = (poolElems + 2 * tElems) * sizeof(float);

    float* scratch = (tier2 || ws_size >= slowNeed) ? (float*)d_ws : out;
    float* pool = scratch;
    float* t2v  = scratch + poolElems;
    float* tSv  = t2v + tElems;
    unsigned short* xT3 = (unsigned short*)((char*)d_ws + hdr);
    float* pp = (float*)((char*)d_ws + hdr + xT_bytes);
    unsigned short* gfrag = (unsigned short*)((char*)d_ws + hdr + xT_bytes + pp_bytes);

    if (tier1) {
        k_xcast<<<N_ * 16, 256, 0, stream>>>(x, xT3, pp);
        k_graphs2f<<<K_ * N_ * 2, 512, 0, stream>>>(pp, W11, b11, W12, b12, W2, b2, W4, b4, A, graphs, gfrag);
        k_biasf<<<N_ * 8, 256, 0, stream>>>(graphs, A, b3, gfrag);
        k_main_fac<<<N_ * 4 * 32, 256, 0, stream>>>(xT3, gfrag, W3, out);
    } else if (tier2) {
        k_xcast<<<N_ * 16, 256, 0, stream>>>(x, xT3, pp);
        k_graphs2f<<<K_ * N_ * 2, 512, 0, stream>>>(pp, W11, b11, W12, b12, W2, b2, W4, b4, A, graphs, (unsigned short*)nullptr);
        k_main_fast2<<<N_ * 32, 256, 0, stream>>>(xT3, graphs, A, W3, b3, out);
    } else {
        k_pool  <<<N_ * C_, 256, 0, stream>>>(x, pool);
        k_tvals <<<K_ * N_, 256, 0, stream>>>(pool, W11, b11, W12, b12, W2, b2, t2v, tSv);
        k_graphs<<<K_ * N_, 256, 0, stream>>>(t2v, tSv, W4, b4, graphs);
        k_main_slow<<<N_ * (O_ / OB) * 4, 256, 0, stream>>>(x, graphs, A, W3, b3, out);
    }
}

// Round 21
// 111.680 us; speedup vs baseline: 1.4741x; 1.0455x over previous
//
#include <hip/hip_runtime.h>
#include <cstdint>
#include <cstddef>

#define N_  32
#define C_  64
#define T_  256
#define V_  25
#define R_  8
#define O_  64
#define K_  5
#define NU_ 17
#define U_  25
#define CV  (C_ * V_)        // 1600
#define OG  2                // o's per block (tier-1 and tier-2 k_main)
#define NB  (OG * 32)        // 64 ncols (tier-2)

#define OUT_ELEMS ((size_t)N_ * O_ * T_ * V_)   // 13,107,200

typedef __attribute__((ext_vector_type(8))) short bf16x8;
typedef __attribute__((ext_vector_type(4))) float f32x4;

static __device__ __forceinline__ unsigned short f2bf(float f) {
    union { float f; unsigned u; } c; c.f = f;
    return (unsigned short)((c.u + 0x8000u) >> 16);
}
static __device__ __forceinline__ float bf2f(unsigned short h) {
    union { unsigned u; float f; } c; c.u = ((unsigned)h) << 16; return c.f;
}
static __device__ __forceinline__ float bf_lo(unsigned d) {
    union { unsigned u; float f; } c; c.u = d << 16; return c.f;
}
static __device__ __forceinline__ float bf_hi(unsigned d) {
    union { unsigned u; float f; } c; c.u = d & 0xFFFF0000u; return c.f;
}
static __device__ __forceinline__ unsigned pk2(float a, float b) {
    union { float f; unsigned u; } ca, cb; ca.f = a; cb.f = b;
    return ((ca.u + 0x8000u) >> 16) | ((cb.u + 0x8000u) & 0xFFFF0000u);
}
static __device__ __forceinline__ unsigned cvtpk(float a, float b) {
    unsigned r;
    asm("v_cvt_pk_bf16_f32 %0, %1, %2" : "=v"(r) : "v"(a), "v"(b));
    return r;
}
static __device__ __forceinline__ bf16x8 asbf(uint4 u) {
    union { uint4 u; bf16x8 h; } c; c.u = u; return c.h;
}
// x2h swizzle class in USHORT units (16B slot = 8 ushorts): bits 3-5.
static __device__ __forceinline__ int clsw(int t) {
    return ((t ^ (t >> 3)) & 7) << 3;
}

// ---------------------------------------------------------------------------
// k_xcast: fragment-native xT3 with cv' = v*64+c ordering:
//   xT3[n][tt(16)][s'(200)][tl(16)][ke(8)],  s' = v*8 + c/8, ke = c&7.
// ---------------------------------------------------------------------------
__global__ void k_xcast(const float* __restrict__ x, unsigned short* __restrict__ xT3,
                        float* __restrict__ pp) {
    __shared__ unsigned short tile[C_][408];   // [c][t*25+v], row 816 B
    int bid = blockIdx.x;
    int n = bid >> 4, tb = bid & 15;
    int tid = threadIdx.x;
    const float* xb = x + (size_t)n * C_ * T_ * V_ + tb * 400;
#pragma unroll
    for (int it = 0; it < 25; ++it) {
        int i = it * 256 + tid;          // < 6400
        int c = i / 100, q = i - c * 100;
        float4 v4 = *(const float4*)(xb + (size_t)c * (T_ * V_) + q * 4);
        uint2 w;
        w.x = pk2(v4.x, v4.y);
        w.y = pk2(v4.z, v4.w);
        *(uint2*)&tile[c][q * 4] = w;
    }
    __syncthreads();
    unsigned short* dstb = xT3 + ((size_t)(n * 16 + tb) * 200) * 128;
    for (int i = tid; i < 200 * 16; i += 256) {
        int sp = i >> 4, tl = i & 15;
        int v = sp >> 3, c0 = (sp & 7) * 8;
        unsigned short h[8];
#pragma unroll
        for (int j = 0; j < 8; ++j) h[j] = tile[c0 + j][tl * 25 + v];
        uint4 pk;
        pk.x = (unsigned)h[0] | ((unsigned)h[1] << 16);
        pk.y = (unsigned)h[2] | ((unsigned)h[3] << 16);
        pk.z = (unsigned)h[4] | ((unsigned)h[5] << 16);
        pk.w = (unsigned)h[6] | ((unsigned)h[7] << 16);
        *(uint4*)(dstb + (size_t)sp * 128 + tl * 8) = pk;
    }
    float* ppd = pp + ((size_t)n * 16 + tb) * CV;
    for (int e = tid; e < CV; e += 256) {
        int c = e / 25, v = e - c * 25;
        float s = 0.f;
#pragma unroll
        for (int t = 0; t < 16; ++t) s += bf2f(tile[c][t * 25 + v]);
        ppd[e] = s;
    }
}

// classic pool (slow tier)
__global__ void k_pool(const float* __restrict__ x, float* __restrict__ pool) {
    int nc = blockIdx.x;
    int t  = threadIdx.x;
    const float* px = x + ((size_t)nc * T_ + t) * V_;
    float acc[V_];
#pragma unroll
    for (int v = 0; v < V_; ++v) acc[v] = px[v];
#pragma unroll
    for (int off = 32; off > 0; off >>= 1) {
#pragma unroll
        for (int v = 0; v < V_; ++v) acc[v] += __shfl_down(acc[v], off, 64);
    }
    __shared__ float sm[4][V_];
    int wave = t >> 6, lane = t & 63;
    if (lane == 0) {
#pragma unroll
        for (int v = 0; v < V_; ++v) sm[wave][v] = acc[v];
    }
    __syncthreads();
    if (t < V_) {
        float s = sm[0][t] + sm[1][t] + sm[2][t] + sm[3][t];
        pool[(size_t)nc * V_ + t] = s * (1.0f / T_);
    }
}

// ---------------------------------------------------------------------------
// k_tvals (slow tier only)
// ---------------------------------------------------------------------------
__global__ void k_tvals(const float* __restrict__ pool,
                        const float* __restrict__ W11, const float* __restrict__ b11,
                        const float* __restrict__ W12, const float* __restrict__ b12,
                        const float* __restrict__ W2,  const float* __restrict__ b2,
                        float* __restrict__ t2o, float* __restrict__ tSo) {
    int kn = blockIdx.x;
    int k = kn / N_, n = kn % N_;
    int tid = threadIdx.x;
    int r = tid >> 5, v = tid & 31;
    if (v >= V_) return;
    const float* pp = pool + (size_t)n * C_ * V_ + v;
    const float* w2 = W2 + ((size_t)k * R_ + r) * C_;
    const float* w1 = ((v < NU_) ? W11 : W12) + ((size_t)k * R_ + r) * C_;
    float a2 = b2[k * R_ + r];
    float a1 = (v < NU_) ? b11[k * R_ + r] : b12[k * R_ + r];
    for (int c = 0; c < C_; ++c) {
        float p = pp[(size_t)c * V_];
        a2 += w2[c] * p;
        a1 += w1[c] * p;
    }
    size_t idx = (((size_t)k * N_ + n) * R_ + r) * V_ + v;
    t2o[idx] = a2;
    tSo[idx] = a1;
}

// ---------------------------------------------------------------------------
// k_graphs (slow tier)
// ---------------------------------------------------------------------------
__global__ void k_graphs(const float* __restrict__ t2v, const float* __restrict__ tSv,
                         const float* __restrict__ W4, const float* __restrict__ b4,
                         float* __restrict__ graphs) {
    int kn = blockIdx.x;
    int k = kn / N_, n = kn % N_;
    int kup = (k + 1) % K_;
    __shared__ float F[R_][V_ * V_];
    __shared__ float w4s[O_][R_];
    __shared__ float b4s[O_];
    int tid = threadIdx.x;
    for (int i = tid; i < O_ * R_; i += 256) w4s[i / R_][i % R_] = W4[(size_t)k * O_ * R_ + i];
    if (tid < O_) b4s[tid] = b4[k * O_ + tid];
    for (int idx = tid; idx < R_ * V_ * V_; idx += 256) {
        int r = idx / (V_ * V_), uv = idx % (V_ * V_);
        int u = uv / V_, v = uv % V_;
        int ks = (u < NU_) ? kup : k;
        size_t base = (((size_t)ks * N_ + n) * R_ + r) * V_;
        F[r][uv] = tanhf(tSv[base + u] - t2v[base + v]);
    }
    __syncthreads();
    float* gout = graphs + ((size_t)k * N_ + n) * O_ * (V_ * V_);
    for (int idx = tid; idx < O_ * V_ * V_; idx += 256) {
        int o = idx / (V_ * V_), uv = idx % (V_ * V_);
        float a = b4s[o];
#pragma unroll
        for (int r = 0; r < R_; ++r) a += w4s[o][r] * F[r][uv];
        gout[idx] = a;
    }
}

// ---------------------------------------------------------------------------
// k_graphs2f: fused pool + tvals + F + graphs; ALSO emits Gfrag (tier 1):
//   gfrag[n][o(64)][u(32)][kv(128)] bf16 = graphs + Adj.
//   Pads (u>=25 rows, kv>=125) left as garbage: u-pads masked at store,
//   kv-pads multiply x2h zeros / excluded from in-kernel bias.
// ---------------------------------------------------------------------------
__global__ void k_graphs2f(const float* __restrict__ pp,
                           const float* __restrict__ W11, const float* __restrict__ b11,
                           const float* __restrict__ W12, const float* __restrict__ b12,
                           const float* __restrict__ W2,  const float* __restrict__ b2,
                           const float* __restrict__ W4,  const float* __restrict__ b4,
                           const float* __restrict__ Adj,
                           float* __restrict__ graphs,
                           unsigned short* __restrict__ gfrag) {
    int bid = blockIdx.x;
    int og = bid & 1;
    int kn = bid >> 1;
    int k = kn / N_, n = kn % N_;
    int kup = (k + 1) % K_;
    __shared__ float poolL[CV];
    __shared__ float t2s[2][R_][V_];
    __shared__ float tSs[2][R_][V_];
    __shared__ float F[R_][V_ * V_];
    __shared__ float w4s[O_][R_];
    __shared__ float b4s[O_];
    int tid = threadIdx.x;
    for (int i = tid; i < O_ * R_; i += 512) w4s[i / R_][i % R_] = W4[(size_t)k * O_ * R_ + i];
    if (tid < O_) b4s[tid] = b4[k * O_ + tid];
    const float* ppn = pp + (size_t)n * 16 * CV;
    for (int i = tid; i < CV; i += 512) {
        float s = 0.f;
#pragma unroll
        for (int tb = 0; tb < 16; ++tb) s += ppn[(size_t)tb * CV + i];
        poolL[i] = s * (1.0f / T_);
    }
    __syncthreads();
    for (int i = tid; i < 2 * R_ * V_; i += 512) {
        int ks = i / (R_ * V_);
        int rem = i - ks * (R_ * V_);
        int r = rem / V_, v = rem - r * V_;
        int kk = ks ? kup : k;
        const float* w2 = W2 + ((size_t)kk * R_ + r) * C_;
        const float* w1 = ((v < NU_) ? W11 : W12) + ((size_t)kk * R_ + r) * C_;
        float a2 = b2[kk * R_ + r];
        float a1 = (v < NU_) ? b11[kk * R_ + r] : b12[kk * R_ + r];
        for (int c = 0; c < C_; ++c) {
            float p = poolL[c * 25 + v];
            a2 += w2[c] * p;
            a1 += w1[c] * p;
        }
        t2s[ks][r][v] = a2;
        tSs[ks][r][v] = a1;
    }
    __syncthreads();
    for (int idx = tid; idx < R_ * V_ * V_; idx += 512) {
        int r = idx / (V_ * V_), uv = idx % (V_ * V_);
        int u = uv / V_, v = uv % V_;
        int ks = (u < NU_) ? 1 : 0;
        F[r][uv] = tanhf(tSs[ks][r][u] - t2s[ks][r][v]);
    }
    __syncthreads();
    float* gout = graphs + ((size_t)k * N_ + n) * O_ * (V_ * V_);
    const int half = O_ * V_ * V_ / 2;
    for (int idx = og * half + tid; idx < (og + 1) * half; idx += 512) {
        int o = idx / (V_ * V_), uv = idx % (V_ * V_);
        float a = b4s[o];
#pragma unroll
        for (int r = 0; r < R_; ++r) a += w4s[o][r] * F[r][uv];
        gout[idx] = a;
        if (gfrag) {
            int u = uv / 25, v = uv - u * 25;
            gfrag[(((size_t)n * 64 + o) * 32 + u) * 128 + k * 25 + v] =
                f2bf(a + Adj[k * 625 + uv]);
        }
    }
}

// ---------------------------------------------------------------------------
// k_main_fac (tier 1): R20 structure + IN-KERNEL BIAS (k_biasf deleted):
//  bias[o][u] = sum_k b3[k,o] * sum_v G — computed per-lane from the
//  already-loaded bfr fragments (lane's rows ARE its output u), with a
//  5-way select for b3[k] (no runtime-indexed arrays) and a 2-step
//  shfl_xor(16/32) reduction across the eg column groups.
//  x2h kv=125..127 = 0 (kv-pad garbage in gfrag contributes nothing).
//  4 blocks/CU, zero barriers, manual ILP. WRITE_SIZE = spill watchdog.
// ---------------------------------------------------------------------------
__global__ __launch_bounds__(256, 4) void k_main_fac(
    const unsigned short* __restrict__ xT3,   // [N][16][200][16][8] bf16 bits
    const unsigned short* __restrict__ gfrag, // [N][64][32][128] bf16
    const float* __restrict__ W3,             // [K][O][C]
    const float* __restrict__ b3,             // [K][O]
    float* __restrict__ out) {

    __shared__ unsigned short x2h[2 * 64 * 128];   // 32 KB

    const int tid = threadIdx.x;
    int raw = blockIdx.x;
    int bid = (raw & 7) * 512 + (raw >> 3);   // XCD swizzle (4096 % 8 == 0)
    const int og = bid & 31;
    const int tb = (bid >> 5) & 3;
    const int n  = bid >> 7;
    const int obase = og * 2;
    const int tgb = tb * 64;
    const int lane = tid & 63;
    const int w = tid >> 6;        // wave = t-tile
    const int lr = lane & 15;
    const int eg = lane >> 4;

    // ---- pre-issue ALL 16 gfrag B-frag loads (independent of stage A) ----
    uint4 bfr[2][2][4];
    {
        const unsigned short* gb = gfrag + (((size_t)n * 64 + obase) * 32) * 128;
#pragma unroll
        for (int o = 0; o < 2; ++o)
#pragma unroll
            for (int nt = 0; nt < 2; ++nt)
#pragma unroll
                for (int ks = 0; ks < 4; ++ks)
                    bfr[o][nt][ks] = *(const uint4*)(gb + (size_t)o * 4096
                                                     + (nt * 16 + lr) * 128 + ks * 32 + eg * 8);
    }
    asm volatile("" ::: "memory");   // pin: loads may not sink below this point

    // ---- b3 scalars (uniform) ----
    float b3r0[K_], b3r1[K_];
#pragma unroll
    for (int k = 0; k < K_; ++k) {
        b3r0[k] = b3[k * O_ + obase];
        b3r1[k] = b3[k * O_ + obase + 1];
    }

    // ---- W3 B-frags in registers (col = lr -> ncol = k*2+o, elems = c) ----
    bf16x8 wb0, wb1;
    {
        short h0[8] = {0,0,0,0,0,0,0,0}, h1[8] = {0,0,0,0,0,0,0,0};
        if (lr < 10) {
            int k = lr >> 1, o = lr & 1;
            const float* wp = W3 + ((size_t)k * O_ + obase + o) * C_;
#pragma unroll
            for (int e = 0; e < 8; ++e) {
                h0[e] = (short)f2bf(wp[eg * 8 + e]);
                h1[e] = (short)f2bf(wp[32 + eg * 8 + e]);
            }
        }
        wb0 = (bf16x8){h0[0], h0[1], h0[2], h0[3], h0[4], h0[5], h0[6], h0[7]};
        wb1 = (bf16x8){h1[0], h1[1], h1[2], h1[3], h1[4], h1[5], h1[6], h1[7]};
    }

    // ---- per-wave pad init: lanes 0..31 cover (o, 16 wave-local t's) ----
    if (lane < 32) {
        int o = lane >> 4, t = w * 16 + (lane & 15);
        int cls = clsw(t);
        int rowb = o * 8192 + t * 128;
        x2h[rowb + (125 ^ cls)] = 0;
        x2h[rowb + (126 ^ cls)] = 0;
        x2h[rowb + (127 ^ cls)] = 0;
    }

    // ---- stage A: 25 per-v GEMMs, explicit 2-deep prefetch ring ----
    {
        const int ttb = tb * 4 + w;
        const unsigned short* pA = xT3 + (size_t)n * (T_ * CV)
                                 + ((size_t)(ttb * 200) + eg) * 128 + lr * 8;
        const int kA = lr >> 1, oA = lr & 1;
        const int tl0 = w * 16 + eg * 4;
        uint4 qa[2], qb[2];
        qa[0] = *(const uint4*)(pA);          qb[0] = *(const uint4*)(pA + 512);
        qa[1] = *(const uint4*)(pA + 1024);   qb[1] = *(const uint4*)(pA + 1536);
#pragma unroll
        for (int v = 0; v < 25; ++v) {
            uint4 a0 = qa[v & 1], a1 = qb[v & 1];
            if (v + 2 < 25) {
                qa[v & 1] = *(const uint4*)(pA + (v + 2) * 1024);
                qb[v & 1] = *(const uint4*)(pA + (v + 2) * 1024 + 512);
            }
            f32x4 d = {0.f, 0.f, 0.f, 0.f};
            d = __builtin_amdgcn_mfma_f32_16x16x32_bf16(asbf(a0), wb0, d, 0, 0, 0);
            d = __builtin_amdgcn_mfma_f32_16x16x32_bf16(asbf(a1), wb1, d, 0, 0, 0);
            if (lr < 10) {
                int kv = kA * 25 + v;
#pragma unroll
                for (int r2 = 0; r2 < 4; ++r2) {
                    int t = tl0 + r2;
                    x2h[oA * 8192 + t * 128 + (kv ^ clsw(t))] = f2bf(d[r2]);
                }
            }
        }
    }
    // NO barrier: stage-B reads are wave-local (same-wave lgkmcnt ordering).

    // ---- in-lane bias from bfr fragments (consumes the preloads AFTER
    //      stage A, so their latency hid under it) ----
    float bsum[2][2];
#pragma unroll
    for (int o = 0; o < 2; ++o)
#pragma unroll
        for (int nt = 0; nt < 2; ++nt) {
            float p = 0.f;
#pragma unroll
            for (int ks = 0; ks < 4; ++ks) {
                const unsigned short* fe = (const unsigned short*)&bfr[o][nt][ks];
#pragma unroll
                for (int e = 0; e < 8; ++e) {
                    int kv = ks * 32 + eg * 8 + e;
                    float wgt = (kv < 25)  ? (o ? b3r1[0] : b3r0[0])
                              : (kv < 50)  ? (o ? b3r1[1] : b3r0[1])
                              : (kv < 75)  ? (o ? b3r1[2] : b3r0[2])
                              : (kv < 100) ? (o ? b3r1[3] : b3r0[3])
                              : (kv < 125) ? (o ? b3r1[4] : b3r0[4])
                                           : 0.f;
                    p += wgt * bf2f(fe[e]);
                }
            }
            p += __shfl_xor(p, 16, 64);
            p += __shfl_xor(p, 32, 64);
            bsum[o][nt] = p;
        }

    // ---- stage B: per wave M=16(t) x N=64(2o x 2nt), K=128 ----
    f32x4 acc[2][2];
#pragma unroll
    for (int o = 0; o < 2; ++o)
#pragma unroll
        for (int nt = 0; nt < 2; ++nt) acc[o][nt] = (f32x4){0.f, 0.f, 0.f, 0.f};

    const int tB = w * 16 + lr;
    const int clsB = clsw(tB);
    const int rowB = tB * 128;
#pragma unroll
    for (int o = 0; o < 2; ++o) {
#pragma unroll
        for (int ks = 0; ks < 4; ++ks) {
            const int kv0 = ks * 32 + eg * 8;
            bf16x8 af = *(const bf16x8*)&x2h[o * 8192 + rowB + (kv0 ^ clsB)];
            acc[o][0] = __builtin_amdgcn_mfma_f32_16x16x32_bf16(af, asbf(bfr[o][0][ks]), acc[o][0], 0, 0, 0);
            acc[o][1] = __builtin_amdgcn_mfma_f32_16x16x32_bf16(af, asbf(bfr[o][1][ks]), acc[o][1], 0, 0, 0);
        }
    }

    // ---- epilogue: C/D col = lr (u), rows = eg*4+r2 (t-in-tile) ----
#pragma unroll
    for (int o = 0; o < 2; ++o) {
        float* ob = out + ((size_t)n * O_ + obase + o) * T_ * V_;
#pragma unroll
        for (int nt = 0; nt < 2; ++nt) {
            int u = nt * 16 + lr;
            if (u < U_) {
                float bv = bsum[o][nt];
#pragma unroll
                for (int r2 = 0; r2 < 4; ++r2) {
                    int t = tgb + w * 16 + eg * 4 + r2;
                    ob[(size_t)t * V_ + u] = acc[o][nt][r2] + bv;
                }
            }
        }
    }
}

// ---------------------------------------------------------------------------
// k_main_fast2 (tier 2 = proven R16 kernel)
// ---------------------------------------------------------------------------
__global__ __launch_bounds__(256, 4) void k_main_fast2(
    const unsigned short* __restrict__ xT3,
    const float* __restrict__ graphs,
    const float* __restrict__ Adj,
    const float* __restrict__ W3,
    const float* __restrict__ b3,
    float* __restrict__ out) {

    __shared__ unsigned short Hs[4][4][NB][8];
    __shared__ uint2 Gbf4[OG * 625];
    __shared__ unsigned short Gbf1[OG * 625];
    __shared__ unsigned short W3kmh[K_ * OG * C_];
    __shared__ float biasS[NB];

    const int tid = threadIdx.x;
    int bid = blockIdx.x;
    bid = (bid & 7) * 128 + (bid >> 3);
    const int obase = (bid & 31) * OG;
    const int n = bid >> 5;
    const int lane = tid & 63;
    const int wv_ = tid >> 6;

    const size_t kstride = (size_t)N_ * O_ * 625;
    for (int i = tid; i < OG * 625; i += 256) {
        int o = i / 625, uv = i - o * 625;
        int u = uv / 25, v = uv - u * 25;
        size_t gb = ((size_t)n * O_ + obase + o) * 625 + uv;
        float g0 = graphs[gb]               + Adj[uv];
        float g1 = graphs[gb + kstride]     + Adj[625 + uv];
        float g2 = graphs[gb + 2 * kstride] + Adj[1250 + uv];
        float g3 = graphs[gb + 3 * kstride] + Adj[1875 + uv];
        float g4 = graphs[gb + 4 * kstride] + Adj[2500 + uv];
        int idx = o * 625 + v * 25 + u;
        uint2 w; w.x = pk2(g0, g1); w.y = pk2(g2, g3);
        Gbf4[idx] = w;
        Gbf1[idx] = f2bf(g4);
    }
    for (int i = tid; i < K_ * OG * C_; i += 256) {
        int k = i / (OG * C_);
        int rem = i - k * (OG * C_);
        int o = rem >> 6, c = rem & 63;
        W3kmh[(k * OG + o) * C_ + c] = f2bf(W3[((size_t)k * O_ + obase + o) * C_ + c]);
    }
    __syncthreads();

    if (tid < NB) {
        int o = tid >> 5, u = tid & 31;
        float bv = 0.f;
        if (u < U_) {
            float s0 = 0.f, s1 = 0.f, s2 = 0.f, s3 = 0.f, s4 = 0.f;
            for (int v = 0; v < V_; ++v) {
                int idx = o * 625 + v * 25 + u;
                uint2 w = Gbf4[idx];
                s0 += bf_lo(w.x); s1 += bf_hi(w.x);
                s2 += bf_lo(w.y); s3 += bf_hi(w.y);
                s4 += bf2f(Gbf1[idx]);
            }
            bv = s0 * b3[0 * O_ + obase + o] + s1 * b3[1 * O_ + obase + o]
               + s2 * b3[2 * O_ + obase + o] + s3 * b3[3 * O_ + obase + o]
               + s4 * b3[4 * O_ + obase + o];
        }
        biasS[tid] = bv;
    }

    const int sl = wv_;
    const int hncol = lane;
    const int ho = hncol >> 5;
    const int hu = hncol & 31;
    const uint2* gp4 = &Gbf4[ho * 625 + hu];
    const unsigned short* gp1 = &Gbf1[ho * 625 + hu];
    const unsigned short* wbh = &W3kmh[ho * C_ + sl * 8];
    char* hwb = (char*)&Hs[0][sl][hncol][0];

    auto h_form = [&](char* hwp, const int parOff, f32x4 g, float g5) {
        float gk[5] = {g[0], g[1], g[2], g[3], g5};
        float h0 = 0.f, h1 = 0.f, h2 = 0.f, h3 = 0.f;
        float h4 = 0.f, h5 = 0.f, h6 = 0.f, h7 = 0.f;
#pragma unroll
        for (int k = 0; k < K_; ++k) {
            uint4 wk = *(const uint4*)(wbh + parOff + k * (OG * C_));
            float gv_ = gk[k];
            h0 += bf_lo(wk.x) * gv_; h1 += bf_hi(wk.x) * gv_;
            h2 += bf_lo(wk.y) * gv_; h3 += bf_hi(wk.y) * gv_;
            h4 += bf_lo(wk.z) * gv_; h5 += bf_hi(wk.z) * gv_;
            h6 += bf_lo(wk.w) * gv_; h7 += bf_hi(wk.w) * gv_;
        }
        uint4 hv;
        hv.x = cvtpk(h0, h1); hv.y = cvtpk(h2, h3);
        hv.z = cvtpk(h4, h5); hv.w = cvtpk(h6, h7);
        *(uint4*)hwp = hv;
    };
    auto ld_g = [&](int voff25, f32x4& g, float& g5) {
        if (hu < U_) {
            uint2 gw = gp4[voff25];
            g[0] = bf_lo(gw.x); g[1] = bf_hi(gw.x);
            g[2] = bf_lo(gw.y); g[3] = bf_hi(gw.y);
            g5 = bf2f(gp1[voff25]);
        } else { g = (f32x4){0.f, 0.f, 0.f, 0.f}; g5 = 0.f; }
    };

    const int wm = wv_;
    const int lr = lane & 15;
    const int eg = lane >> 4;

    f32x4 acc[4][4];
#pragma unroll
    for (int mt = 0; mt < 4; ++mt)
#pragma unroll
        for (int nt = 0; nt < 4; ++nt) acc[mt][nt] = (f32x4){0.f, 0.f, 0.f, 0.f};

    const unsigned short* An = xT3 + (size_t)n * (T_ * CV);
    const unsigned short* a0 = An + ((size_t)((wm * 4 + 0) * 200 + eg)) * 128 + lr * 8;
    const unsigned short* a1 = a0 + 200 * 128;
    const unsigned short* a2 = a0 + 400 * 128;
    const unsigned short* a3 = a0 + 600 * 128;
    const char* hrb = (const char*)&Hs[0][eg][lr][0];

    auto consume = [&](int sub, int bufb) {
        uint4 av0 = *(const uint4*)(a0 + sub);
        uint4 av1 = *(const uint4*)(a1 + sub);
        uint4 av2 = *(const uint4*)(a2 + sub);
        uint4 av3 = *(const uint4*)(a3 + sub);
        bf16x8 b[4];
#pragma unroll
        for (int nt = 0; nt < 4; ++nt)
            b[nt] = *(const bf16x8*)(hrb + bufb + nt * 256);
        __builtin_amdgcn_s_setprio(1);
        union { uint4 u; bf16x8 h; } c0, c1, c2, c3;
        c0.u = av0; c1.u = av1; c2.u = av2; c3.u = av3;
#pragma unroll
        for (int nt = 0; nt < 4; ++nt) acc[0][nt] = __builtin_amdgcn_mfma_f32_16x16x32_bf16(c0.h, b[nt], acc[0][nt], 0, 0, 0);
#pragma unroll
        for (int nt = 0; nt < 4; ++nt) acc[1][nt] = __builtin_amdgcn_mfma_f32_16x16x32_bf16(c1.h, b[nt], acc[1][nt], 0, 0, 0);
#pragma unroll
        for (int nt = 0; nt < 4; ++nt) acc[2][nt] = __builtin_amdgcn_mfma_f32_16x16x32_bf16(c2.h, b[nt], acc[2][nt], 0, 0, 0);
#pragma unroll
        for (int nt = 0; nt < 4; ++nt) acc[3][nt] = __builtin_amdgcn_mfma_f32_16x16x32_bf16(c3.h, b[nt], acc[3][nt], 0, 0, 0);
        __builtin_amdgcn_s_setprio(0);
    };

    f32x4 gv; float gv5;
    ld_g(0, gv, gv5);
    h_form(hwb, 0, gv, gv5);
    h_form(hwb + 4096, 32, gv, gv5);
    __syncthreads();

    for (int kc2 = 0; kc2 < 25; ++kc2) {
        const int rb = (kc2 & 1) * 8192;
        const int wb = 8192 - rb;
        if (kc2 + 1 < 25) ld_g((kc2 + 1) * 25, gv, gv5);
        consume(0, rb);
        consume(512, rb + 4096);
        if (kc2 + 1 < 25) {
            h_form(hwb + wb, 0, gv, gv5);
            h_form(hwb + wb + 4096, 32, gv, gv5);
        }
        __syncthreads();
        a0 += 1024; a1 += 1024; a2 += 1024; a3 += 1024;
    }

#pragma unroll
    for (int nt = 0; nt < 4; ++nt) {
        int ncol = nt * 16 + lr;
        int ol = ncol >> 5;
        int u  = ncol & 31;
        if (u < U_) {
            float bv = biasS[ncol];
            float* ob = out + ((size_t)n * O_ + obase + ol) * T_ * V_ + u;
#pragma unroll
            for (int mt = 0; mt < 4; ++mt) {
                int t0 = wm * 64 + mt * 16 + eg * 4;
#pragma unroll
                for (int r2 = 0; r2 < 4; ++r2)
                    ob[(size_t)(t0 + r2) * V_] = acc[mt][nt][r2] + bv;
            }
        }
    }
}

// ---------------------------------------------------------------------------
// k_main_slow (tier 3, proven R2 path)
// ---------------------------------------------------------------------------
#define OB 4
#define TB 64
__global__ __launch_bounds__(256, 1) void k_main_slow(
    const float* __restrict__ x, const float* __restrict__ graphs,
    const float* __restrict__ A, const float* __restrict__ W3,
    const float* __restrict__ b3, float* __restrict__ out) {
    int bid = blockIdx.x;
    int tb = bid & 3;
    int ob = (bid >> 2) & 15;
    int n  = bid >> 6;
    int tid = threadIdx.x;
    int ol = tid >> 6;
    int tl = tid & 63;
    int t = tb * TB + tl;
    int o = ob * OB + ol;

    __shared__ float Gs[K_][OB][V_][28];
    __shared__ float W3s[K_][OB][C_];
    __shared__ float b3s[K_][OB];

    for (int i = tid; i < K_ * OB * V_ * V_; i += 256) {
        int k   = i / (OB * V_ * V_);
        int rem = i % (OB * V_ * V_);
        int oo  = rem / (V_ * V_);
        int uv  = rem % (V_ * V_);
        Gs[k][oo][uv / V_][uv % V_] =
            graphs[(((size_t)k * N_ + n) * O_ + ob * OB + oo) * (V_ * V_) + uv]
            + A[k * V_ * V_ + uv];
    }
    for (int i = tid; i < K_ * OB * C_; i += 256) {
        int k   = i / (OB * C_);
        int rem = i % (OB * C_);
        int oo  = rem / C_, c = rem % C_;
        W3s[k][oo][c] = W3[((size_t)k * O_ + ob * OB + oo) * C_ + c];
    }
    if (tid < K_ * OB) b3s[tid / OB][tid % OB] = b3[(tid / OB) * O_ + ob * OB + tid % OB];
    __syncthreads();

    float x2[K_][V_];
#pragma unroll
    for (int k = 0; k < K_; ++k)
#pragma unroll
        for (int v = 0; v < V_; ++v) x2[k][v] = b3s[k][ol];

    const float* xb = x + ((size_t)n * C_ * T_ + t) * V_;
    for (int c = 0; c < C_; ++c) {
        const float* p = xb + (size_t)c * T_ * V_;
        float xv[V_];
#pragma unroll
        for (int v = 0; v < V_; ++v) xv[v] = p[v];
#pragma unroll
        for (int k = 0; k < K_; ++k) {
            float w = W3s[k][ol][c];
#pragma unroll
            for (int v = 0; v < V_; ++v) x2[k][v] += w * xv[v];
        }
    }

    float acc[V_];
#pragma unroll
    for (int u = 0; u < V_; ++u) acc[u] = 0.0f;
#pragma unroll
    for (int k = 0; k < K_; ++k) {
#pragma unroll
        for (int u = 0; u < V_; ++u) {
            const float* gr = &Gs[k][ol][u][0];
            float s = 0.0f;
#pragma unroll
            for (int v = 0; v < V_; ++v) s += gr[v] * x2[k][v];
            acc[u] += s;
        }
    }
    float* po = out + (((size_t)n * O_ + o) * T_ + t) * V_;
#pragma unroll
    for (int u = 0; u < V_; ++u) po[u] = acc[u];
}

// ---------------------------------------------------------------------------
extern "C" void kernel_launch(void* const* d_in, const int* in_sizes, int n_in,
                              void* d_out, int out_size, void* d_ws, size_t ws_size,
                              hipStream_t stream) {
    const float* x   = (const float*)d_in[0];
    const float* A   = (const float*)d_in[1];
    const float* W11 = (const float*)d_in[2];
    const float* b11 = (const float*)d_in[3];
    const float* W12 = (const float*)d_in[4];
    const float* b12 = (const float*)d_in[5];
    const float* W2  = (const float*)d_in[6];
    const float* b2  = (const float*)d_in[7];
    const float* W3  = (const float*)d_in[8];
    const float* b3  = (const float*)d_in[9];
    const float* W4  = (const float*)d_in[10];
    const float* b4  = (const float*)d_in[11];

    float* out    = (float*)d_out;
    float* graphs = out + OUT_ELEMS;   // second tuple element

    const size_t xT_bytes = sizeof(unsigned short) * (size_t)N_ * T_ * CV;  // 26.2 MB
    const size_t pp_bytes = sizeof(float) * (size_t)N_ * 16 * CV;           //  3.3 MB
    const size_t gf_bytes = sizeof(unsigned short) * (size_t)N_ * 64 * 32 * 128; // 16.8 MB
    const size_t hdr      = (size_t)(1 << 20);
    const bool tier1 = (ws_size >= hdr + xT_bytes + pp_bytes + gf_bytes);
    const bool tier2 = (ws_size >= hdr + xT_bytes + pp_bytes);

    const size_t poolElems = (size_t)N_ * C_ * V_;
    const size_t tElems    = (size_t)K_ * N_ * R_ * V_;
    const size_t slowNeed  = (poolElems + 2 * tElems) * sizeof(float);

    float* scratch = (tier2 || ws_size >= slowNeed) ? (float*)d_ws : out;
    float* pool = scratch;
    float* t2v  = scratch + poolElems;
    float* tSv  = t2v + tElems;
    unsigned short* xT3 = (unsigned short*)((char*)d_ws + hdr);
    float* pp = (float*)((char*)d_ws + hdr + xT_bytes);
    unsigned short* gfrag = (unsigned short*)((char*)d_ws + hdr + xT_bytes + pp_bytes);

    if (tier1) {
        k_xcast<<<N_ * 16, 256, 0, stream>>>(x, xT3, pp);
        k_graphs2f<<<K_ * N_ * 2, 512, 0, stream>>>(pp, W11, b11, W12, b12, W2, b2, W4, b4, A, graphs, gfrag);
        k_main_fac<<<N_ * 4 * 32, 256, 0, stream>>>(xT3, gfrag, W3, b3, out);
    } else if (tier2) {
        k_xcast<<<N_ * 16, 256, 0, stream>>>(x, xT3, pp);
        k_graphs2f<<<K_ * N_ * 2, 512, 0, stream>>>(pp, W11, b11, W12, b12, W2, b2, W4, b4, A, graphs, (unsigned short*)nullptr);
        k_main_fast2<<<N_ * 32, 256, 0, stream>>>(xT3, graphs, A, W3, b3, out);
    } else {
        k_pool  <<<N_ * C_, 256, 0, stream>>>(x, pool);
        k_tvals <<<K_ * N_, 256, 0, stream>>>(pool, W11, b11, W12, b12, W2, b2, t2v, tSv);
        k_graphs<<<K_ * N_, 256, 0, stream>>>(t2v, tSv, W4, b4, graphs);
        k_main_slow<<<N_ * (O_ / OB) * 4, 256, 0, stream>>>(x, graphs, A, W3, b3, out);
    }
}